// Round 2
// baseline (211.434 us; speedup 1.0000x reference)
//
#include <hip/hip_runtime.h>

// _GSPostProcessor: out = D^{-1/2} (topk20(relu(A) + dope*1e-4)*relu(A) + I) D^{-1/2}
// B=16, N=2048, K=20.
// topk_fast : wave-per-row, per-lane top-4 cache, DPP/permlane u32 argmax extraction (no LDS).
//             Rare hard cases (cache underflow / cross-lane value-bit tie) -> flag.
// cleanup   : re-runs the exact (R1-verified) shfl-based algorithm for flagged rows only.
// scatter   : block-per-row LDS scatter -> dense coalesced write.

static constexpr int N    = 2048;
static constexpr int KSEL = 20;
static constexpr int NR   = 16 * 2048;   // B*N rows
static constexpr unsigned SENT = 0u;     // empty-cache sentinel (loses every max; ==0.0f keys get flagged)

typedef unsigned int uint2v __attribute__((ext_vector_type(2)));

// ---------- cross-lane u32 max over 64 lanes: DPP ror within 16, permlane swaps across ----------
#if __has_builtin(__builtin_amdgcn_mov_dpp)
#define ROR_MAX(x, n) (x) = max((x), (unsigned)__builtin_amdgcn_mov_dpp((int)(x), 0x120 + (n), 0xF, 0xF, false))
#else
#define ROR_MAX(x, n) (x) = max((x), (unsigned)__shfl_xor((int)(x), (n)))
#endif

__device__ __forceinline__ unsigned wave_max_u32(unsigned x) {
  ROR_MAX(x, 1);
  ROR_MAX(x, 2);
  ROR_MAX(x, 4);
  ROR_MAX(x, 8);
#if __has_builtin(__builtin_amdgcn_permlane16_swap)
  { uint2v r = __builtin_amdgcn_permlane16_swap(x, x, false, false);
    x = max((unsigned)r[0], (unsigned)r[1]); }
#else
  x = max(x, (unsigned)__shfl_xor((int)x, 16));
#endif
#if __has_builtin(__builtin_amdgcn_permlane32_swap)
  { uint2v r = __builtin_amdgcn_permlane32_swap(x, x, false, false);
    x = max((unsigned)r[0], (unsigned)r[1]); }
#else
  x = max(x, (unsigned)__shfl_xor((int)x, 32));
#endif
  return x;
}

__device__ __forceinline__ int read_lane_i32(int v, int srclane) {
#if __has_builtin(__builtin_amdgcn_readlane)
  return __builtin_amdgcn_readlane(v, srclane);
#else
  return __shfl(v, srclane, 64);
#endif
}

// ---------- branchless top-4 insertion, u32 keys + small index, stable (earlier stays above) ----------
__device__ __forceinline__ void ins4u(unsigned vc, int cc,
                                      unsigned& t0, unsigned& t1, unsigned& t2, unsigned& t3,
                                      int& c0, int& c1, int& c2, int& c3) {
  bool b0 = vc > t0;
  unsigned d0 = b0 ? t0 : vc; int e0 = b0 ? c0 : cc;
  t0 = b0 ? vc : t0;          c0 = b0 ? cc : c0;
  bool b1 = d0 > t1;
  unsigned d1 = b1 ? t1 : d0; int e1 = b1 ? c1 : e0;
  t1 = b1 ? d0 : t1;          c1 = b1 ? e0 : c1;
  bool b2 = d1 > t2;
  unsigned d2 = b2 ? t2 : d1; int e2 = b2 ? c2 : e1;
  t2 = b2 ? d1 : t2;          c2 = b2 ? e1 : c2;
  bool b3 = d2 > t3;
  t3 = b3 ? d2 : t3;          c3 = b3 ? e2 : c3;
}

// ---------- original (R1-verified) float insertion + serial shfl extraction: exact fallback ----------
__device__ __forceinline__ void ins4(float vc, int jc,
                                     float& t0, float& t1, float& t2, float& t3,
                                     int& j0, int& j1, int& j2, int& j3) {
  bool b0 = vc > t0;
  float d0 = b0 ? t0 : vc; int e0 = b0 ? j0 : jc;
  t0 = b0 ? vc : t0;       j0 = b0 ? jc : j0;
  bool b1 = d0 > t1;
  float d1 = b1 ? t1 : d0; int e1 = b1 ? j1 : e0;
  t1 = b1 ? d0 : t1;       j1 = b1 ? e0 : j1;
  bool b2 = d1 > t2;
  float d2 = b2 ? t2 : d1; int e2 = b2 ? j2 : e1;
  t2 = b2 ? d1 : t2;       j2 = b2 ? e1 : j2;
  bool b3 = d2 > t3;
  t3 = b3 ? d2 : t3;       j3 = b3 ? e2 : j3;
}

__device__ __forceinline__ int wave_topk_exact(const float* __restrict__ Arow,
                                               const float* __restrict__ Drow,
                                               int lane) {
  float v[32];
  const float4* A4 = reinterpret_cast<const float4*>(Arow);
  const float4* D4 = reinterpret_cast<const float4*>(Drow);
#pragma unroll
  for (int c4 = 0; c4 < 8; ++c4) {
    float4 a = A4[c4 * 64 + lane];
    float4 d = D4[c4 * 64 + lane];
    v[c4 * 4 + 0] = __fadd_rn(fmaxf(a.x, 0.0f), __fmul_rn(d.x, 1e-4f));
    v[c4 * 4 + 1] = __fadd_rn(fmaxf(a.y, 0.0f), __fmul_rn(d.y, 1e-4f));
    v[c4 * 4 + 2] = __fadd_rn(fmaxf(a.z, 0.0f), __fmul_rn(d.z, 1e-4f));
    v[c4 * 4 + 3] = __fadd_rn(fmaxf(a.w, 0.0f), __fmul_rn(d.w, 1e-4f));
  }
  float t0 = -1.f, t1 = -1.f, t2 = -1.f, t3 = -1.f;
  int   j0 = 0,    j1 = 0,    j2 = 0,    j3 = 0;
#pragma unroll
  for (int c = 0; c < 32; ++c) {
    int jc = ((c >> 2) << 8) | (lane << 2) | (c & 3);
    ins4(v[c], jc, t0, t1, t2, t3, j0, j1, j2, j3);
  }
  unsigned consumed = 0;
  int jmine = 0;
#pragma unroll 1
  for (int it = 0; it < KSEL; ++it) {
    if (__any(t0 < 0.0f)) {
      if (t0 < 0.0f) {
        t0 = t1 = t2 = t3 = -1.f; j0 = j1 = j2 = j3 = 0;
#pragma unroll
        for (int c = 0; c < 32; ++c) {
          float vc = ((consumed >> c) & 1u) ? -1.0f : v[c];
          int jc = ((c >> 2) << 8) | (lane << 2) | (c & 3);
          ins4(vc, jc, t0, t1, t2, t3, j0, j1, j2, j3);
        }
      }
    }
    float m = t0;
#pragma unroll
    for (int off = 32; off; off >>= 1) m = fmaxf(m, __shfl_xor(m, off));
    int cj = (t0 == m) ? j0 : 0x7fffffff;
#pragma unroll
    for (int off = 32; off; off >>= 1) cj = min(cj, __shfl_xor(cj, off));
    if (lane == it) jmine = cj;
    if (((cj >> 2) & 63) == lane) {
      int c = ((cj >> 8) << 2) | (cj & 3);
      consumed |= (1u << c);
      t0 = t1; j0 = j1; t1 = t2; j1 = j2; t2 = t3; j2 = j3; t3 = -1.f; j3 = 0;
    }
  }
  return jmine;
}

// ---------- fast pass 1 ----------
__global__ void __launch_bounds__(256)
topk_fast(const float* __restrict__ A, const float* __restrict__ D,
          float* __restrict__ wval, int* __restrict__ widx,
          float* __restrict__ wdinv, int* __restrict__ wflag) {
  int lane = threadIdx.x & 63;
  int r = blockIdx.x * 4 + (threadIdx.x >> 6);
  size_t base = (size_t)r * N;
  const float4* A4 = reinterpret_cast<const float4*>(A + base);
  const float4* D4 = reinterpret_cast<const float4*>(D + base);

  unsigned t0 = SENT, t1 = SENT, t2 = SENT, t3 = SENT;
  int c0 = 0, c1 = 0, c2 = 0, c3 = 0;
#pragma unroll
  for (int c4 = 0; c4 < 8; ++c4) {
    float4 a = A4[c4 * 64 + lane];
    float4 d = D4[c4 * 64 + lane];
    // match numpy exactly: separate round for mul and add (no fma contraction)
    unsigned k0 = __float_as_uint(__fadd_rn(fmaxf(a.x, 0.0f), __fmul_rn(d.x, 1e-4f)));
    unsigned k1 = __float_as_uint(__fadd_rn(fmaxf(a.y, 0.0f), __fmul_rn(d.y, 1e-4f)));
    unsigned k2 = __float_as_uint(__fadd_rn(fmaxf(a.z, 0.0f), __fmul_rn(d.z, 1e-4f)));
    unsigned k3 = __float_as_uint(__fadd_rn(fmaxf(a.w, 0.0f), __fmul_rn(d.w, 1e-4f)));
    ins4u(k0, c4 * 4 + 0, t0, t1, t2, t3, c0, c1, c2, c3);
    ins4u(k1, c4 * 4 + 1, t0, t1, t2, t3, c0, c1, c2, c3);
    ins4u(k2, c4 * 4 + 2, t0, t1, t2, t3, c0, c1, c2, c3);
    ins4u(k3, c4 * 4 + 3, t0, t1, t2, t3, c0, c1, c2, c3);
  }

  bool lanebad = false;
  bool tiebad  = false;
  int jmine = 0;
#pragma unroll
  for (int it = 0; it < KSEL; ++it) {
    lanebad |= (t0 == SENT);                 // cache underflow -> needs exact redo
    unsigned M = wave_max_u32(t0);
    unsigned long long mask = __ballot(t0 == M);
    tiebad |= ((mask & (mask - 1ull)) != 0ull);  // cross-lane value-bit tie -> exact redo
    int w = (int)__builtin_ctzll(mask);          // wave-uniform winner lane
    int cw = read_lane_i32(c0, w);
    int jw = ((cw >> 2) << 8) | (w << 2) | (cw & 3);   // j = c4*256 + lane*4 + q
    jmine = (lane == it) ? jw : jmine;
    bool pop = (lane == w);
    t0 = pop ? t1 : t0;  c0 = pop ? c1 : c0;
    t1 = pop ? t2 : t1;  c1 = pop ? c2 : c1;
    t2 = pop ? t3 : t2;  c2 = pop ? c3 : c2;
    t3 = pop ? SENT : t3;
  }

  float val = 0.0f;
  if (lane < KSEL) val = fmaxf(A[base + jmine], 0.0f);   // exact relu value (L2 hit)
  float s = (lane < KSEL) ? val : 0.0f;
#pragma unroll
  for (int off = 32; off; off >>= 1) s += __shfl_xor(s, off);
  float dinv = (float)(1.0 / sqrt(1.0 + (double)s));     // row sum >= 1, never inf

  if (lane < KSEL) {
    wval[r * KSEL + lane] = val;
    widx[r * KSEL + lane] = jmine;
  }
  int bad = (__any(lanebad) ? 1 : 0) | (tiebad ? 1 : 0);
  if (lane == 0) {
    wdinv[r] = dinv;
    wflag[r] = bad;
  }
}

// ---------- cleanup: exact redo of flagged rows only ----------
__global__ void __launch_bounds__(256)
cleanup_rows(const float* __restrict__ A, const float* __restrict__ D,
             const int* __restrict__ wflag,
             float* __restrict__ wval, int* __restrict__ widx,
             float* __restrict__ wdinv) {
  int lane = threadIdx.x & 63;
  int r = blockIdx.x * 4 + (threadIdx.x >> 6);
  if (wflag[r] == 0) return;                 // wave-uniform early exit
  size_t base = (size_t)r * N;
  int jm = wave_topk_exact(A + base, D + base, lane);
  float val = 0.0f;
  if (lane < KSEL) val = fmaxf(A[base + jm], 0.0f);
  float s = (lane < KSEL) ? val : 0.0f;
#pragma unroll
  for (int off = 32; off; off >>= 1) s += __shfl_xor(s, off);
  float dinv = (float)(1.0 / sqrt(1.0 + (double)s));
  if (lane < KSEL) {
    wval[r * KSEL + lane] = val;
    widx[r * KSEL + lane] = jm;
  }
  if (lane == 0) wdinv[r] = dinv;
}

// ---------- pass 2: dense scatter (unchanged, R1-verified) ----------
__global__ void __launch_bounds__(256)
scatter_pass2(const float* __restrict__ wval, const int* __restrict__ widx,
              const float* __restrict__ wdinv, float* __restrict__ out) {
  __shared__ float row[N];
  int r = blockIdx.x;
  int i = r & (N - 1);
  int tid = threadIdx.x;
  float4* rv = reinterpret_cast<float4*>(row);
  float4 z = make_float4(0.f, 0.f, 0.f, 0.f);
  rv[tid] = z;
  rv[tid + 256] = z;
  __syncthreads();
  float di = wdinv[r];
  if (tid < KSEL) {
    int j   = widx[r * KSEL + tid];
    float v = wval[r * KSEL + tid];
    float dj = wdinv[(r & ~(N - 1)) + j];
    atomicAdd(&row[j], di * v * dj);          // may collide with diagonal only
  } else if (tid == KSEL) {
    atomicAdd(&row[i], di * di);              // the +I term
  }
  __syncthreads();
  float4* o4 = reinterpret_cast<float4*>(out + (size_t)r * N);
  o4[tid] = rv[tid];
  o4[tid + 256] = rv[tid + 256];
}

// ---------- fallback (tiny ws): exact single-fused path, R1-verified ----------
__global__ void __launch_bounds__(256)
topk_exact_pass1(const float* __restrict__ A, const float* __restrict__ D,
                 float* __restrict__ wdinv) {
  int lane = threadIdx.x & 63;
  int r = blockIdx.x * 4 + (threadIdx.x >> 6);
  size_t base = (size_t)r * N;
  int jm = wave_topk_exact(A + base, D + base, lane);
  float val = 0.0f;
  if (lane < KSEL) val = fmaxf(A[base + jm], 0.0f);
  float s = (lane < KSEL) ? val : 0.0f;
#pragma unroll
  for (int off = 32; off; off >>= 1) s += __shfl_xor(s, off);
  float dinv = (float)(1.0 / sqrt(1.0 + (double)s));
  if (lane == 0) wdinv[r] = dinv;
}

__global__ void __launch_bounds__(256)
fallback_pass2(const float* __restrict__ A, const float* __restrict__ D,
               const float* __restrict__ wdinv, float* __restrict__ out) {
  __shared__ float rows[4][N];
  int lane = threadIdx.x & 63;
  int w = threadIdx.x >> 6;
  int r = blockIdx.x * 4 + w;
  size_t base = (size_t)r * N;
  int i = r & (N - 1);
  int jm = wave_topk_exact(A + base, D + base, lane);
  float val = 0.0f;
  if (lane < KSEL) val = fmaxf(A[base + jm], 0.0f);
  float s = (lane < KSEL) ? val : 0.0f;
#pragma unroll
  for (int off = 32; off; off >>= 1) s += __shfl_xor(s, off);
  float di = (float)(1.0 / sqrt(1.0 + (double)s));
  float4* rv = reinterpret_cast<float4*>(rows[w]);
  float4 z = make_float4(0.f, 0.f, 0.f, 0.f);
#pragma unroll
  for (int q = 0; q < 8; ++q) rv[q * 64 + lane] = z;
  __syncthreads();
  if (lane < KSEL) {
    float dj = wdinv[(r & ~(N - 1)) + jm];
    atomicAdd(&rows[w][jm], di * val * dj);
  } else if (lane == KSEL) {
    atomicAdd(&rows[w][i], di * di);
  }
  __syncthreads();
  float4* o4 = reinterpret_cast<float4*>(out + base);
#pragma unroll
  for (int q = 0; q < 8; ++q) o4[q * 64 + lane] = rv[q * 64 + lane];
}

extern "C" void kernel_launch(void* const* d_in, const int* in_sizes, int n_in,
                              void* d_out, int out_size, void* d_ws, size_t ws_size,
                              hipStream_t stream) {
  const float* A = (const float*)d_in[0];
  const float* D = (const float*)d_in[1];
  float* out = (float*)d_out;
  char* ws = (char*)d_ws;
  size_t bytes_val  = (size_t)NR * KSEL * sizeof(float);
  size_t bytes_idx  = (size_t)NR * KSEL * sizeof(int);
  size_t bytes_dinv = (size_t)NR * sizeof(float);
  size_t bytes_flag = (size_t)NR * sizeof(int);
  if (ws_size >= bytes_val + bytes_idx + bytes_dinv + bytes_flag) {
    float* wval  = (float*)ws;
    int*   widx  = (int*)(ws + bytes_val);
    float* wdinv = (float*)(ws + bytes_val + bytes_idx);
    int*   wflag = (int*)(ws + bytes_val + bytes_idx + bytes_dinv);
    topk_fast<<<NR / 4, 256, 0, stream>>>(A, D, wval, widx, wdinv, wflag);
    cleanup_rows<<<NR / 4, 256, 0, stream>>>(A, D, wflag, wval, widx, wdinv);
    scatter_pass2<<<NR, 256, 0, stream>>>(wval, widx, wdinv, out);
  } else {
    float* wdinv = (float*)ws;
    topk_exact_pass1<<<NR / 4, 256, 0, stream>>>(A, D, wdinv);
    fallback_pass2<<<NR / 4, 256, 0, stream>>>(A, D, wdinv, out);
  }
}

// Round 3
// 206.968 us; speedup vs baseline: 1.0216x; 1.0216x over previous
//
#include <hip/hip_runtime.h>

// _GSPostProcessor: out = D^{-1/2} (topk20(relu(A) + dope*1e-4)*relu(A) + I) D^{-1/2}
// B=16, N=2048, K=20.
// topk_fast   : wave-per-row. Threshold (T=2.05) candidate compaction via ballot+mbcnt
//               into LDS (<=64 cands, ~41 expected), then 64-lane bitonic sort of
//               (keybits<<32 | 2047-j) descending -> lanes 0..19 hold exact top-20 in
//               rank order with exact jax tie semantics. Rows with C<20 or C>64 ->
//               compact bad-list, redone exactly by cleanup_list (R1-proven path).
// cleanup_list: 128 waves grid-stride the bad-list (expected ~15 rows).
// scatter     : block-per-row LDS scatter -> dense coalesced write (R1-proven).

static constexpr int N    = 2048;
static constexpr int KSEL = 20;
static constexpr int NR   = 16 * 2048;   // B*N rows

typedef unsigned int uint2v __attribute__((ext_vector_type(2)));

// ---------------- cross-lane primitives ----------------
#if __has_builtin(__builtin_amdgcn_mov_dpp)
#define XD(v, ctrl) ((unsigned)__builtin_amdgcn_mov_dpp((int)(v), (ctrl), 0xF, 0xF, false))
#else
#define XD(v, ctrl) ((unsigned)__shfl_xor((int)(v), ((ctrl) == 0xB1 ? 1 : 2)))
#endif
#if __has_builtin(__builtin_amdgcn_ds_swizzle)
#define XS(v, imm) ((unsigned)__builtin_amdgcn_ds_swizzle((int)(v), (imm)))
#else
#define XS(v, imm) ((unsigned)__shfl_xor((int)(v), (((imm) >> 10) & 0x1F)))
#endif

__device__ __forceinline__ int lanecnt_below(unsigned long long m) {
#if __has_builtin(__builtin_amdgcn_mbcnt_lo) && __has_builtin(__builtin_amdgcn_mbcnt_hi)
  return (int)__builtin_amdgcn_mbcnt_hi((unsigned)(m >> 32),
              __builtin_amdgcn_mbcnt_lo((unsigned)m, 0u));
#else
  int lane = threadIdx.x & 63;
  return (int)__popcll(m & ((1ull << lane) - 1ull));
#endif
}

// compare-exchange: {A,B} = {self, partner} (order irrelevant); keep max iff km.
__device__ __forceinline__ void cex(unsigned& hi, unsigned& lo,
                                    unsigned Ahi, unsigned Alo,
                                    unsigned Bhi, unsigned Blo, bool km) {
  unsigned long long Av = ((unsigned long long)Ahi << 32) | Alo;
  unsigned long long Bv = ((unsigned long long)Bhi << 32) | Blo;
  bool sel = (km == (Av > Bv));
  hi = sel ? Ahi : Bhi;
  lo = sel ? Alo : Blo;
}

#define KM(K2, J) ((((lane & (J)) == 0)) != (((lane & (K2)) != 0)))
#define EX1(K2)  cex(hi, lo, hi, lo, XD(hi, 0xB1), XD(lo, 0xB1), KM(K2, 1))
#define EX2(K2)  cex(hi, lo, hi, lo, XD(hi, 0x4E), XD(lo, 0x4E), KM(K2, 2))
#define EX4(K2)  cex(hi, lo, hi, lo, XS(hi, 0x101F), XS(lo, 0x101F), KM(K2, 4))
#define EX8(K2)  cex(hi, lo, hi, lo, XS(hi, 0x201F), XS(lo, 0x201F), KM(K2, 8))
#if __has_builtin(__builtin_amdgcn_permlane16_swap)
#define EX16(K2) { uint2v r_ = __builtin_amdgcn_permlane16_swap(hi, hi, false, false); \
                   uint2v s_ = __builtin_amdgcn_permlane16_swap(lo, lo, false, false); \
                   cex(hi, lo, (unsigned)r_[0], (unsigned)s_[0], (unsigned)r_[1], (unsigned)s_[1], KM(K2, 16)); }
#else
#define EX16(K2) cex(hi, lo, hi, lo, (unsigned)__shfl_xor((int)hi, 16), (unsigned)__shfl_xor((int)lo, 16), KM(K2, 16))
#endif
#if __has_builtin(__builtin_amdgcn_permlane32_swap)
#define EX32(K2) { uint2v r_ = __builtin_amdgcn_permlane32_swap(hi, hi, false, false); \
                   uint2v s_ = __builtin_amdgcn_permlane32_swap(lo, lo, false, false); \
                   cex(hi, lo, (unsigned)r_[0], (unsigned)s_[0], (unsigned)r_[1], (unsigned)s_[1], KM(K2, 32)); }
#else
#define EX32(K2) cex(hi, lo, hi, lo, (unsigned)__shfl_xor((int)hi, 32), (unsigned)__shfl_xor((int)lo, 32), KM(K2, 32))
#endif

// ---------------- exact (R1-proven) slow path ----------------
__device__ __forceinline__ void ins4(float vc, int jc,
                                     float& t0, float& t1, float& t2, float& t3,
                                     int& j0, int& j1, int& j2, int& j3) {
  bool b0 = vc > t0;
  float d0 = b0 ? t0 : vc; int e0 = b0 ? j0 : jc;
  t0 = b0 ? vc : t0;       j0 = b0 ? jc : j0;
  bool b1 = d0 > t1;
  float d1 = b1 ? t1 : d0; int e1 = b1 ? j1 : e0;
  t1 = b1 ? d0 : t1;       j1 = b1 ? e0 : j1;
  bool b2 = d1 > t2;
  float d2 = b2 ? t2 : d1; int e2 = b2 ? j2 : e1;
  t2 = b2 ? d1 : t2;       j2 = b2 ? e1 : j2;
  bool b3 = d2 > t3;
  t3 = b3 ? d2 : t3;       j3 = b3 ? e2 : j3;
}

__device__ __forceinline__ int wave_topk_exact(const float* __restrict__ Arow,
                                               const float* __restrict__ Drow,
                                               int lane) {
  float v[32];
  const float4* A4 = reinterpret_cast<const float4*>(Arow);
  const float4* D4 = reinterpret_cast<const float4*>(Drow);
#pragma unroll
  for (int c4 = 0; c4 < 8; ++c4) {
    float4 a = A4[c4 * 64 + lane];
    float4 d = D4[c4 * 64 + lane];
    v[c4 * 4 + 0] = __fadd_rn(fmaxf(a.x, 0.0f), __fmul_rn(d.x, 1e-4f));
    v[c4 * 4 + 1] = __fadd_rn(fmaxf(a.y, 0.0f), __fmul_rn(d.y, 1e-4f));
    v[c4 * 4 + 2] = __fadd_rn(fmaxf(a.z, 0.0f), __fmul_rn(d.z, 1e-4f));
    v[c4 * 4 + 3] = __fadd_rn(fmaxf(a.w, 0.0f), __fmul_rn(d.w, 1e-4f));
  }
  float t0 = -1.f, t1 = -1.f, t2 = -1.f, t3 = -1.f;
  int   j0 = 0,    j1 = 0,    j2 = 0,    j3 = 0;
#pragma unroll
  for (int c = 0; c < 32; ++c) {
    int jc = ((c >> 2) << 8) | (lane << 2) | (c & 3);
    ins4(v[c], jc, t0, t1, t2, t3, j0, j1, j2, j3);
  }
  unsigned consumed = 0;
  int jmine = 0;
#pragma unroll 1
  for (int it = 0; it < KSEL; ++it) {
    if (__any(t0 < 0.0f)) {
      if (t0 < 0.0f) {
        t0 = t1 = t2 = t3 = -1.f; j0 = j1 = j2 = j3 = 0;
#pragma unroll
        for (int c = 0; c < 32; ++c) {
          float vc = ((consumed >> c) & 1u) ? -1.0f : v[c];
          int jc = ((c >> 2) << 8) | (lane << 2) | (c & 3);
          ins4(vc, jc, t0, t1, t2, t3, j0, j1, j2, j3);
        }
      }
    }
    float m = t0;
#pragma unroll
    for (int off = 32; off; off >>= 1) m = fmaxf(m, __shfl_xor(m, off));
    int cj = (t0 == m) ? j0 : 0x7fffffff;
#pragma unroll
    for (int off = 32; off; off >>= 1) cj = min(cj, __shfl_xor(cj, off));
    if (lane == it) jmine = cj;
    if (((cj >> 2) & 63) == lane) {
      int c = ((cj >> 8) << 2) | (cj & 3);
      consumed |= (1u << c);
      t0 = t1; j0 = j1; t1 = t2; j1 = j2; t2 = t3; j2 = j3; t3 = -1.f; j3 = 0;
    }
  }
  return jmine;
}

// ---------------- fast pass 1 ----------------
__global__ void __launch_bounds__(256)
topk_fast(const float* __restrict__ A, const float* __restrict__ D,
          float* __restrict__ wval, int* __restrict__ widx,
          float* __restrict__ wdinv, int* __restrict__ badcnt,
          int* __restrict__ badlist) {
  __shared__ unsigned long long cand[4][64];
  const float T = 2.05f;
  int lane = threadIdx.x & 63;
  int w = threadIdx.x >> 6;
  int r = blockIdx.x * 4 + w;
  size_t base = (size_t)r * N;
  const float4* A4 = reinterpret_cast<const float4*>(A + base);
  const float4* D4 = reinterpret_cast<const float4*>(D + base);

  cand[w][lane] = 0ull;      // padding: sorts to the bottom (keys are > T > 0)
  int cnt = 0;

#define PROC(KQ, C4, Q) do {                                                   \
    bool c_ = (KQ) > T;                                                        \
    unsigned long long bal_ = __ballot(c_);                                    \
    int pos_ = cnt + lanecnt_below(bal_);                                      \
    if (c_ && pos_ < 64) {                                                     \
      int j_ = ((C4) << 8) | (lane << 2) | (Q);                                \
      cand[w][pos_] = ((unsigned long long)__float_as_uint(KQ) << 32) |        \
                      (unsigned)(2047 - j_);                                   \
    }                                                                          \
    cnt += (int)__popcll(bal_);                                                \
  } while (0)

#pragma unroll
  for (int c4 = 0; c4 < 8; ++c4) {
    float4 a = A4[c4 * 64 + lane];
    float4 d = D4[c4 * 64 + lane];
    // match numpy exactly: separate round for mul and add (no fma contraction)
    float k0 = __fadd_rn(fmaxf(a.x, 0.0f), __fmul_rn(d.x, 1e-4f));
    float k1 = __fadd_rn(fmaxf(a.y, 0.0f), __fmul_rn(d.y, 1e-4f));
    float k2 = __fadd_rn(fmaxf(a.z, 0.0f), __fmul_rn(d.z, 1e-4f));
    float k3 = __fadd_rn(fmaxf(a.w, 0.0f), __fmul_rn(d.w, 1e-4f));
    PROC(k0, c4, 0);
    PROC(k1, c4, 1);
    PROC(k2, c4, 2);
    PROC(k3, c4, 3);
  }
#undef PROC

  // wave-private LDS: writes land in-order; fence before cross-lane read
  __asm__ __volatile__("s_waitcnt lgkmcnt(0)" ::: "memory");
  unsigned long long kv = cand[w][lane];
  unsigned hi = (unsigned)(kv >> 32), lo = (unsigned)kv;

  // 64-lane bitonic sort, descending by (value, 2047-j)  -> exact jax tie semantics
  EX1(2);
  EX2(4);  EX1(4);
  EX4(8);  EX2(8);  EX1(8);
  EX8(16); EX4(16); EX2(16); EX1(16);
  EX16(32); EX8(32); EX4(32); EX2(32); EX1(32);
  EX32(64); EX16(64); EX8(64); EX4(64); EX2(64); EX1(64);

  int jsel = 2047 - (int)lo;             // valid for lanes < cnt; padding -> 2047 (in range)
  float val = 0.0f;
  if (lane < KSEL) val = fmaxf(A[base + jsel], 0.0f);   // exact relu value (L1-hot)
  float s = (lane < KSEL) ? val : 0.0f;
#pragma unroll
  for (int off = 32; off; off >>= 1) s += __shfl_xor(s, off);
  float dinv = (float)(1.0 / sqrt(1.0 + (double)s));    // row sum >= 1, never inf

  if (lane < KSEL) {
    wval[r * KSEL + lane] = val;
    widx[r * KSEL + lane] = jsel;
  }
  bool bad = (cnt < KSEL) || (cnt > 64);
  if (lane == 0) {
    wdinv[r] = dinv;
    if (bad) {
      int p = atomicAdd(badcnt, 1);
      badlist[p] = r;
    }
  }
}

// ---------------- cleanup: exact redo of listed rows ----------------
__global__ void __launch_bounds__(256)
cleanup_list(const float* __restrict__ A, const float* __restrict__ D,
             const int* __restrict__ badcnt, const int* __restrict__ badlist,
             float* __restrict__ wval, int* __restrict__ widx,
             float* __restrict__ wdinv) {
  int lane = threadIdx.x & 63;
  int gw = (blockIdx.x * 256 + threadIdx.x) >> 6;   // global wave id
  int nw = gridDim.x * 4;
  int nbad = badcnt[0];
  for (int i = gw; i < nbad; i += nw) {
    int r = badlist[i];
    size_t base = (size_t)r * N;
    int jm = wave_topk_exact(A + base, D + base, lane);
    float val = 0.0f;
    if (lane < KSEL) val = fmaxf(A[base + jm], 0.0f);
    float s = (lane < KSEL) ? val : 0.0f;
#pragma unroll
    for (int off = 32; off; off >>= 1) s += __shfl_xor(s, off);
    float dinv = (float)(1.0 / sqrt(1.0 + (double)s));
    if (lane < KSEL) {
      wval[r * KSEL + lane] = val;
      widx[r * KSEL + lane] = jm;
    }
    if (lane == 0) wdinv[r] = dinv;
  }
}

// ---------------- pass 2: dense scatter (R1-proven) ----------------
__global__ void __launch_bounds__(256)
scatter_pass2(const float* __restrict__ wval, const int* __restrict__ widx,
              const float* __restrict__ wdinv, float* __restrict__ out) {
  __shared__ float row[N];
  int r = blockIdx.x;
  int i = r & (N - 1);
  int tid = threadIdx.x;
  float4* rv = reinterpret_cast<float4*>(row);
  float4 z = make_float4(0.f, 0.f, 0.f, 0.f);
  rv[tid] = z;
  rv[tid + 256] = z;
  __syncthreads();
  float di = wdinv[r];
  if (tid < KSEL) {
    int j   = widx[r * KSEL + tid];
    float v = wval[r * KSEL + tid];
    float dj = wdinv[(r & ~(N - 1)) + j];
    atomicAdd(&row[j], di * v * dj);          // may collide with diagonal only
  } else if (tid == KSEL) {
    atomicAdd(&row[i], di * di);              // the +I term
  }
  __syncthreads();
  float4* o4 = reinterpret_cast<float4*>(out + (size_t)r * N);
  o4[tid] = rv[tid];
  o4[tid + 256] = rv[tid + 256];
}

// ---------------- fallback (tiny ws): exact fused path, R1-proven ----------------
__global__ void __launch_bounds__(256)
topk_exact_pass1(const float* __restrict__ A, const float* __restrict__ D,
                 float* __restrict__ wdinv) {
  int lane = threadIdx.x & 63;
  int r = blockIdx.x * 4 + (threadIdx.x >> 6);
  size_t base = (size_t)r * N;
  int jm = wave_topk_exact(A + base, D + base, lane);
  float val = 0.0f;
  if (lane < KSEL) val = fmaxf(A[base + jm], 0.0f);
  float s = (lane < KSEL) ? val : 0.0f;
#pragma unroll
  for (int off = 32; off; off >>= 1) s += __shfl_xor(s, off);
  float dinv = (float)(1.0 / sqrt(1.0 + (double)s));
  if (lane == 0) wdinv[r] = dinv;
}

__global__ void __launch_bounds__(256)
fallback_pass2(const float* __restrict__ A, const float* __restrict__ D,
               const float* __restrict__ wdinv, float* __restrict__ out) {
  __shared__ float rows[4][N];
  int lane = threadIdx.x & 63;
  int w = threadIdx.x >> 6;
  int r = blockIdx.x * 4 + w;
  size_t base = (size_t)r * N;
  int i = r & (N - 1);
  int jm = wave_topk_exact(A + base, D + base, lane);
  float val = 0.0f;
  if (lane < KSEL) val = fmaxf(A[base + jm], 0.0f);
  float s = (lane < KSEL) ? val : 0.0f;
#pragma unroll
  for (int off = 32; off; off >>= 1) s += __shfl_xor(s, off);
  float di = (float)(1.0 / sqrt(1.0 + (double)s));
  float4* rv = reinterpret_cast<float4*>(rows[w]);
  float4 z = make_float4(0.f, 0.f, 0.f, 0.f);
#pragma unroll
  for (int q = 0; q < 8; ++q) rv[q * 64 + lane] = z;
  __syncthreads();
  if (lane < KSEL) {
    float dj = wdinv[(r & ~(N - 1)) + jm];
    atomicAdd(&rows[w][jm], di * val * dj);
  } else if (lane == KSEL) {
    atomicAdd(&rows[w][i], di * di);
  }
  __syncthreads();
  float4* o4 = reinterpret_cast<float4*>(out + base);
#pragma unroll
  for (int q = 0; q < 8; ++q) o4[q * 64 + lane] = rv[q * 64 + lane];
}

extern "C" void kernel_launch(void* const* d_in, const int* in_sizes, int n_in,
                              void* d_out, int out_size, void* d_ws, size_t ws_size,
                              hipStream_t stream) {
  const float* A = (const float*)d_in[0];
  const float* D = (const float*)d_in[1];
  float* out = (float*)d_out;
  char* ws = (char*)d_ws;
  size_t off_val  = 0;
  size_t off_idx  = off_val + (size_t)NR * KSEL * sizeof(float);
  size_t off_dinv = off_idx + (size_t)NR * KSEL * sizeof(int);
  size_t off_cnt  = off_dinv + (size_t)NR * sizeof(float);
  size_t off_list = off_cnt + 128;
  size_t total    = off_list + (size_t)NR * sizeof(int);
  if (ws_size >= total) {
    float* wval   = (float*)(ws + off_val);
    int*   widx   = (int*)(ws + off_idx);
    float* wdinv  = (float*)(ws + off_dinv);
    int*   badcnt = (int*)(ws + off_cnt);
    int*   badlist= (int*)(ws + off_list);
    hipMemsetAsync(badcnt, 0, sizeof(int), stream);
    topk_fast<<<NR / 4, 256, 0, stream>>>(A, D, wval, widx, wdinv, badcnt, badlist);
    cleanup_list<<<32, 256, 0, stream>>>(A, D, badcnt, badlist, wval, widx, wdinv);
    scatter_pass2<<<NR, 256, 0, stream>>>(wval, widx, wdinv, out);
  } else {
    float* wdinv = (float*)ws;
    topk_exact_pass1<<<NR / 4, 256, 0, stream>>>(A, D, wdinv);
    fallback_pass2<<<NR / 4, 256, 0, stream>>>(A, D, wdinv, out);
  }
}

// Round 4
// 199.679 us; speedup vs baseline: 1.0589x; 1.0365x over previous
//
#include <hip/hip_runtime.h>

// _GSPostProcessor: out = D^{-1/2} (topk20(relu(A) + dope*1e-4)*relu(A) + I) D^{-1/2}
// B=16, N=2048, K=20.
// topk_fast    : wave-per-row. Whole row (A+D) loaded into registers via 16 explicit
//                float4 loads (MLP!). Candidates (key > T=2.05) pushed to LDS via
//                atomicAdd slot alloc (no serial chain; order canonicalized by sort).
//                64-lane bitonic sort of (keybits<<32 | 2047-j) desc -> lanes 0..19
//                hold exact top-20, jax tie semantics. cnt<20 or cnt>64 -> wflag.
// cleanup_flags: 512 waves scan wflag, redo flagged rows (~15-20) with R1-exact path.
// scatter_pass2: block-per-row LDS scatter -> dense coalesced write (R1-proven).

static constexpr int N    = 2048;
static constexpr int KSEL = 20;
static constexpr int NR   = 16 * 2048;   // B*N rows

typedef unsigned int uint2v __attribute__((ext_vector_type(2)));

// ---------------- cross-lane primitives ----------------
#if __has_builtin(__builtin_amdgcn_mov_dpp)
#define XD(v, ctrl) ((unsigned)__builtin_amdgcn_mov_dpp((int)(v), (ctrl), 0xF, 0xF, false))
#else
#define XD(v, ctrl) ((unsigned)__shfl_xor((int)(v), ((ctrl) == 0xB1 ? 1 : 2)))
#endif
#if __has_builtin(__builtin_amdgcn_ds_swizzle)
#define XS(v, imm) ((unsigned)__builtin_amdgcn_ds_swizzle((int)(v), (imm)))
#else
#define XS(v, imm) ((unsigned)__shfl_xor((int)(v), (((imm) >> 10) & 0x1F)))
#endif

// compare-exchange: {A,B} = {self, partner} (order irrelevant); keep max iff km.
__device__ __forceinline__ void cex(unsigned& hi, unsigned& lo,
                                    unsigned Ahi, unsigned Alo,
                                    unsigned Bhi, unsigned Blo, bool km) {
  unsigned long long Av = ((unsigned long long)Ahi << 32) | Alo;
  unsigned long long Bv = ((unsigned long long)Bhi << 32) | Blo;
  bool sel = (km == (Av > Bv));
  hi = sel ? Ahi : Bhi;
  lo = sel ? Alo : Blo;
}

#define KM(K2, J) ((((lane & (J)) == 0)) != (((lane & (K2)) != 0)))
#define EX1(K2)  cex(hi, lo, hi, lo, XD(hi, 0xB1), XD(lo, 0xB1), KM(K2, 1))
#define EX2(K2)  cex(hi, lo, hi, lo, XD(hi, 0x4E), XD(lo, 0x4E), KM(K2, 2))
#define EX4(K2)  cex(hi, lo, hi, lo, XS(hi, 0x101F), XS(lo, 0x101F), KM(K2, 4))
#define EX8(K2)  cex(hi, lo, hi, lo, XS(hi, 0x201F), XS(lo, 0x201F), KM(K2, 8))
#if __has_builtin(__builtin_amdgcn_permlane16_swap)
#define EX16(K2) { uint2v r_ = __builtin_amdgcn_permlane16_swap(hi, hi, false, false); \
                   uint2v s_ = __builtin_amdgcn_permlane16_swap(lo, lo, false, false); \
                   cex(hi, lo, (unsigned)r_[0], (unsigned)s_[0], (unsigned)r_[1], (unsigned)s_[1], KM(K2, 16)); }
#else
#define EX16(K2) cex(hi, lo, hi, lo, (unsigned)__shfl_xor((int)hi, 16), (unsigned)__shfl_xor((int)lo, 16), KM(K2, 16))
#endif
#if __has_builtin(__builtin_amdgcn_permlane32_swap)
#define EX32(K2) { uint2v r_ = __builtin_amdgcn_permlane32_swap(hi, hi, false, false); \
                   uint2v s_ = __builtin_amdgcn_permlane32_swap(lo, lo, false, false); \
                   cex(hi, lo, (unsigned)r_[0], (unsigned)s_[0], (unsigned)r_[1], (unsigned)s_[1], KM(K2, 32)); }
#else
#define EX32(K2) cex(hi, lo, hi, lo, (unsigned)__shfl_xor((int)hi, 32), (unsigned)__shfl_xor((int)lo, 32), KM(K2, 32))
#endif

// ---------------- exact (R1-proven) slow path ----------------
__device__ __forceinline__ void ins4(float vc, int jc,
                                     float& t0, float& t1, float& t2, float& t3,
                                     int& j0, int& j1, int& j2, int& j3) {
  bool b0 = vc > t0;
  float d0 = b0 ? t0 : vc; int e0 = b0 ? j0 : jc;
  t0 = b0 ? vc : t0;       j0 = b0 ? jc : j0;
  bool b1 = d0 > t1;
  float d1 = b1 ? t1 : d0; int e1 = b1 ? j1 : e0;
  t1 = b1 ? d0 : t1;       j1 = b1 ? e0 : j1;
  bool b2 = d1 > t2;
  float d2 = b2 ? t2 : d1; int e2 = b2 ? j2 : e1;
  t2 = b2 ? d1 : t2;       j2 = b2 ? e1 : j2;
  bool b3 = d2 > t3;
  t3 = b3 ? d2 : t3;       j3 = b3 ? e2 : j3;
}

__device__ __forceinline__ int wave_topk_exact(const float* __restrict__ Arow,
                                               const float* __restrict__ Drow,
                                               int lane) {
  float v[32];
  const float4* A4 = reinterpret_cast<const float4*>(Arow);
  const float4* D4 = reinterpret_cast<const float4*>(Drow);
#pragma unroll
  for (int c4 = 0; c4 < 8; ++c4) {
    float4 a = A4[c4 * 64 + lane];
    float4 d = D4[c4 * 64 + lane];
    v[c4 * 4 + 0] = __fadd_rn(fmaxf(a.x, 0.0f), __fmul_rn(d.x, 1e-4f));
    v[c4 * 4 + 1] = __fadd_rn(fmaxf(a.y, 0.0f), __fmul_rn(d.y, 1e-4f));
    v[c4 * 4 + 2] = __fadd_rn(fmaxf(a.z, 0.0f), __fmul_rn(d.z, 1e-4f));
    v[c4 * 4 + 3] = __fadd_rn(fmaxf(a.w, 0.0f), __fmul_rn(d.w, 1e-4f));
  }
  float t0 = -1.f, t1 = -1.f, t2 = -1.f, t3 = -1.f;
  int   j0 = 0,    j1 = 0,    j2 = 0,    j3 = 0;
#pragma unroll
  for (int c = 0; c < 32; ++c) {
    int jc = ((c >> 2) << 8) | (lane << 2) | (c & 3);
    ins4(v[c], jc, t0, t1, t2, t3, j0, j1, j2, j3);
  }
  unsigned consumed = 0;
  int jmine = 0;
#pragma unroll 1
  for (int it = 0; it < KSEL; ++it) {
    if (__any(t0 < 0.0f)) {
      if (t0 < 0.0f) {
        t0 = t1 = t2 = t3 = -1.f; j0 = j1 = j2 = j3 = 0;
#pragma unroll
        for (int c = 0; c < 32; ++c) {
          float vc = ((consumed >> c) & 1u) ? -1.0f : v[c];
          int jc = ((c >> 2) << 8) | (lane << 2) | (c & 3);
          ins4(vc, jc, t0, t1, t2, t3, j0, j1, j2, j3);
        }
      }
    }
    float m = t0;
#pragma unroll
    for (int off = 32; off; off >>= 1) m = fmaxf(m, __shfl_xor(m, off));
    int cj = (t0 == m) ? j0 : 0x7fffffff;
#pragma unroll
    for (int off = 32; off; off >>= 1) cj = min(cj, __shfl_xor(cj, off));
    if (lane == it) jmine = cj;
    if (((cj >> 2) & 63) == lane) {
      int c = ((cj >> 8) << 2) | (cj & 3);
      consumed |= (1u << c);
      t0 = t1; j0 = j1; t1 = t2; j1 = j2; t2 = t3; j2 = j3; t3 = -1.f; j3 = 0;
    }
  }
  return jmine;
}

// ---------------- fast pass 1 ----------------
__global__ void __launch_bounds__(256)
topk_fast(const float* __restrict__ A, const float* __restrict__ D,
          float* __restrict__ wval, int* __restrict__ widx,
          float* __restrict__ wdinv, int* __restrict__ wflag) {
  __shared__ unsigned long long cand[4][64];
  __shared__ unsigned scnt[4];
  const float T = 2.05f;
  int lane = threadIdx.x & 63;
  int w = threadIdx.x >> 6;
  int r = blockIdx.x * 4 + w;
  size_t base = (size_t)r * N;
  const float4* A4 = reinterpret_cast<const float4*>(A + base);
  const float4* D4 = reinterpret_cast<const float4*>(D + base);

  // Issue the whole row as 16 independent loads (MLP: all in flight at once).
  float4 a0 = A4[lane],       a1 = A4[64 + lane],  a2 = A4[128 + lane], a3 = A4[192 + lane];
  float4 a4 = A4[256 + lane], a5 = A4[320 + lane], a6 = A4[384 + lane], a7 = A4[448 + lane];
  float4 d0 = D4[lane],       d1 = D4[64 + lane],  d2 = D4[128 + lane], d3 = D4[192 + lane];
  float4 d4 = D4[256 + lane], d5 = D4[320 + lane], d6 = D4[384 + lane], d7 = D4[448 + lane];

  cand[w][lane] = 0ull;        // padding sorts to the bottom (real keys > T > 0)
  if (lane == 0) scnt[w] = 0u;

  // Candidate push: no cross-slice dependency; LDS atomic allocates a slot.
  // Slot order is nondeterministic but the bitonic sort canonicalizes it.
#define PUSH1(AV, DV, J) do {                                                  \
    float k_ = __fadd_rn(fmaxf((AV), 0.0f), __fmul_rn((DV), 1e-4f));           \
    if (k_ > T) {                                                              \
      unsigned p_ = atomicAdd(&scnt[w], 1u);                                   \
      if (p_ < 64u)                                                            \
        cand[w][p_] = ((unsigned long long)__float_as_uint(k_) << 32) |        \
                      (unsigned)(2047 - (J));                                  \
    }                                                                          \
  } while (0)
#define PUSH4(AA, DD, C4) do {                                                 \
    int jb_ = ((C4) << 8) | (lane << 2);                                       \
    PUSH1(AA.x, DD.x, jb_ + 0);                                                \
    PUSH1(AA.y, DD.y, jb_ + 1);                                                \
    PUSH1(AA.z, DD.z, jb_ + 2);                                                \
    PUSH1(AA.w, DD.w, jb_ + 3);                                                \
  } while (0)

  PUSH4(a0, d0, 0); PUSH4(a1, d1, 1); PUSH4(a2, d2, 2); PUSH4(a3, d3, 3);
  PUSH4(a4, d4, 4); PUSH4(a5, d5, 5); PUSH4(a6, d6, 6); PUSH4(a7, d7, 7);
#undef PUSH4
#undef PUSH1

  // wave-private LDS; drain DS pipe before cross-lane reads
  __asm__ __volatile__("s_waitcnt lgkmcnt(0)" ::: "memory");
  unsigned cnt = scnt[w];
  unsigned long long kv = cand[w][lane];
  unsigned hi = (unsigned)(kv >> 32), lo = (unsigned)kv;

  // 64-lane bitonic sort, descending by (value, 2047-j) -> exact jax tie semantics
  EX1(2);
  EX2(4);  EX1(4);
  EX4(8);  EX2(8);  EX1(8);
  EX8(16); EX4(16); EX2(16); EX1(16);
  EX16(32); EX8(32); EX4(32); EX2(32); EX1(32);
  EX32(64); EX16(64); EX8(64); EX4(64); EX2(64); EX1(64);

  int jsel = 2047 - (int)lo;             // padding -> 2047 (in range)
  float val = 0.0f;
  if (lane < KSEL) val = fmaxf(A[base + jsel], 0.0f);   // exact relu value (L1/L2 hit)
  float s = (lane < KSEL) ? val : 0.0f;
#pragma unroll
  for (int off = 32; off; off >>= 1) s += __shfl_xor(s, off);
  float dinv = (float)(1.0 / sqrt(1.0 + (double)s));    // row sum >= 1, never inf

  if (lane < KSEL) {
    wval[r * KSEL + lane] = val;
    widx[r * KSEL + lane] = jsel;
  }
  if (lane == 0) {
    wdinv[r] = dinv;
    wflag[r] = (cnt < (unsigned)KSEL) || (cnt > 64u);
  }
}

// ---------------- cleanup: scan flags, redo flagged rows exactly ----------------
__global__ void __launch_bounds__(256)
cleanup_flags(const float* __restrict__ A, const float* __restrict__ D,
              const int* __restrict__ wflag,
              float* __restrict__ wval, int* __restrict__ widx,
              float* __restrict__ wdinv) {
  int lane = threadIdx.x & 63;
  int gw = (blockIdx.x * 256 + threadIdx.x) >> 6;   // global wave id, 0..511
  int rbase = gw * 64;
  if (rbase >= NR) return;
  int f = wflag[rbase + lane];
  unsigned long long m = __ballot(f != 0);
  while (m) {
    int b = (int)__builtin_ctzll(m);
    m &= m - 1ull;
    int r = rbase + b;
    size_t base = (size_t)r * N;
    int jm = wave_topk_exact(A + base, D + base, lane);
    float val = 0.0f;
    if (lane < KSEL) val = fmaxf(A[base + jm], 0.0f);
    float s = (lane < KSEL) ? val : 0.0f;
#pragma unroll
    for (int off = 32; off; off >>= 1) s += __shfl_xor(s, off);
    float dinv = (float)(1.0 / sqrt(1.0 + (double)s));
    if (lane < KSEL) {
      wval[r * KSEL + lane] = val;
      widx[r * KSEL + lane] = jm;
    }
    if (lane == 0) wdinv[r] = dinv;
  }
}

// ---------------- pass 2: dense scatter (R1-proven) ----------------
__global__ void __launch_bounds__(256)
scatter_pass2(const float* __restrict__ wval, const int* __restrict__ widx,
              const float* __restrict__ wdinv, float* __restrict__ out) {
  __shared__ float row[N];
  int r = blockIdx.x;
  int i = r & (N - 1);
  int tid = threadIdx.x;
  float4* rv = reinterpret_cast<float4*>(row);
  float4 z = make_float4(0.f, 0.f, 0.f, 0.f);
  rv[tid] = z;
  rv[tid + 256] = z;
  __syncthreads();
  float di = wdinv[r];
  if (tid < KSEL) {
    int j   = widx[r * KSEL + tid];
    float v = wval[r * KSEL + tid];
    float dj = wdinv[(r & ~(N - 1)) + j];
    atomicAdd(&row[j], di * v * dj);          // may collide with diagonal only
  } else if (tid == KSEL) {
    atomicAdd(&row[i], di * di);              // the +I term
  }
  __syncthreads();
  float4* o4 = reinterpret_cast<float4*>(out + (size_t)r * N);
  o4[tid] = rv[tid];
  o4[tid + 256] = rv[tid + 256];
}

// ---------------- fallback (tiny ws): exact fused path, R1-proven ----------------
__global__ void __launch_bounds__(256)
topk_exact_pass1(const float* __restrict__ A, const float* __restrict__ D,
                 float* __restrict__ wdinv) {
  int lane = threadIdx.x & 63;
  int r = blockIdx.x * 4 + (threadIdx.x >> 6);
  size_t base = (size_t)r * N;
  int jm = wave_topk_exact(A + base, D + base, lane);
  float val = 0.0f;
  if (lane < KSEL) val = fmaxf(A[base + jm], 0.0f);
  float s = (lane < KSEL) ? val : 0.0f;
#pragma unroll
  for (int off = 32; off; off >>= 1) s += __shfl_xor(s, off);
  float dinv = (float)(1.0 / sqrt(1.0 + (double)s));
  if (lane == 0) wdinv[r] = dinv;
}

__global__ void __launch_bounds__(256)
fallback_pass2(const float* __restrict__ A, const float* __restrict__ D,
               const float* __restrict__ wdinv, float* __restrict__ out) {
  __shared__ float rows[4][N];
  int lane = threadIdx.x & 63;
  int w = threadIdx.x >> 6;
  int r = blockIdx.x * 4 + w;
  size_t base = (size_t)r * N;
  int i = r & (N - 1);
  int jm = wave_topk_exact(A + base, D + base, lane);
  float val = 0.0f;
  if (lane < KSEL) val = fmaxf(A[base + jm], 0.0f);
  float s = (lane < KSEL) ? val : 0.0f;
#pragma unroll
  for (int off = 32; off; off >>= 1) s += __shfl_xor(s, off);
  float di = (float)(1.0 / sqrt(1.0 + (double)s));
  float4* rv = reinterpret_cast<float4*>(rows[w]);
  float4 z = make_float4(0.f, 0.f, 0.f, 0.f);
#pragma unroll
  for (int q = 0; q < 8; ++q) rv[q * 64 + lane] = z;
  __syncthreads();
  if (lane < KSEL) {
    float dj = wdinv[(r & ~(N - 1)) + jm];
    atomicAdd(&rows[w][jm], di * val * dj);
  } else if (lane == KSEL) {
    atomicAdd(&rows[w][i], di * di);
  }
  __syncthreads();
  float4* o4 = reinterpret_cast<float4*>(out + base);
#pragma unroll
  for (int q = 0; q < 8; ++q) o4[q * 64 + lane] = rv[q * 64 + lane];
}

extern "C" void kernel_launch(void* const* d_in, const int* in_sizes, int n_in,
                              void* d_out, int out_size, void* d_ws, size_t ws_size,
                              hipStream_t stream) {
  const float* A = (const float*)d_in[0];
  const float* D = (const float*)d_in[1];
  float* out = (float*)d_out;
  char* ws = (char*)d_ws;
  size_t off_val  = 0;
  size_t off_idx  = off_val + (size_t)NR * KSEL * sizeof(float);
  size_t off_dinv = off_idx + (size_t)NR * KSEL * sizeof(int);
  size_t off_flag = off_dinv + (size_t)NR * sizeof(float);
  size_t total    = off_flag + (size_t)NR * sizeof(int);
  if (ws_size >= total) {
    float* wval  = (float*)(ws + off_val);
    int*   widx  = (int*)(ws + off_idx);
    float* wdinv = (float*)(ws + off_dinv);
    int*   wflag = (int*)(ws + off_flag);
    topk_fast<<<NR / 4, 256, 0, stream>>>(A, D, wval, widx, wdinv, wflag);
    cleanup_flags<<<128, 256, 0, stream>>>(A, D, wflag, wval, widx, wdinv);
    scatter_pass2<<<NR, 256, 0, stream>>>(wval, widx, wdinv, out);
  } else {
    float* wdinv = (float*)ws;
    topk_exact_pass1<<<NR / 4, 256, 0, stream>>>(A, D, wdinv);
    fallback_pass2<<<NR / 4, 256, 0, stream>>>(A, D, wdinv, out);
  }
}

// Round 5
// 168.610 us; speedup vs baseline: 1.2540x; 1.1843x over previous
//
#include <hip/hip_runtime.h>

// _GSPostProcessor: out = D^{-1/2} (topk20(relu(A) + dope*1e-4)*relu(A) + I) D^{-1/2}
// B=16, N=2048, K=20.
// Key insight (R5): output depends only on the top-20 SET and relu(A) values.
//   dope shifts keys by fmul_rn(d,1e-4) in [0,1e-4] (exact bound, d in [0,1)).
//   If after sorting a'=relu(a) alone: a(19) > fadd(a(20),1e-4) and a(19) > fadd(T,1e-4),
//   the doped top-20 set == undoped top-20 set, exactly. Else -> flag -> exact cleanup.
//   => pass1 never reads dope (256 MB saved), and the sorted keys ARE the output values.
// topk_fast    : wave-per-row, threshold T=2.05 candidate push (LDS atomic slots),
//                64-lane bitonic sort desc by (a'bits, 2047-j). Lanes 0..19 = top-20.
// cleanup_flags: redo flagged rows (~0.3%) with the R1-proven exact path (reads A+D).
// scatter_pass2: block-per-row LDS scatter -> dense coalesced write (R1-proven).

static constexpr int N    = 2048;
static constexpr int KSEL = 20;
static constexpr int NR   = 16 * 2048;   // B*N rows

typedef unsigned int uint2v __attribute__((ext_vector_type(2)));

// ---------------- cross-lane primitives ----------------
#if __has_builtin(__builtin_amdgcn_mov_dpp)
#define XD(v, ctrl) ((unsigned)__builtin_amdgcn_mov_dpp((int)(v), (ctrl), 0xF, 0xF, false))
#else
#define XD(v, ctrl) ((unsigned)__shfl_xor((int)(v), ((ctrl) == 0xB1 ? 1 : 2)))
#endif
#if __has_builtin(__builtin_amdgcn_ds_swizzle)
#define XS(v, imm) ((unsigned)__builtin_amdgcn_ds_swizzle((int)(v), (imm)))
#else
#define XS(v, imm) ((unsigned)__shfl_xor((int)(v), (((imm) >> 10) & 0x1F)))
#endif

__device__ __forceinline__ unsigned read_lane_u32(unsigned v, int srclane) {
#if __has_builtin(__builtin_amdgcn_readlane)
  return (unsigned)__builtin_amdgcn_readlane((int)v, srclane);
#else
  return (unsigned)__shfl((int)v, srclane, 64);
#endif
}

// compare-exchange: {A,B} = {self, partner} (order irrelevant); keep max iff km.
__device__ __forceinline__ void cex(unsigned& hi, unsigned& lo,
                                    unsigned Ahi, unsigned Alo,
                                    unsigned Bhi, unsigned Blo, bool km) {
  unsigned long long Av = ((unsigned long long)Ahi << 32) | Alo;
  unsigned long long Bv = ((unsigned long long)Bhi << 32) | Blo;
  bool sel = (km == (Av > Bv));
  hi = sel ? Ahi : Bhi;
  lo = sel ? Alo : Blo;
}

#define KM(K2, J) ((((lane & (J)) == 0)) != (((lane & (K2)) != 0)))
#define EX1(K2)  cex(hi, lo, hi, lo, XD(hi, 0xB1), XD(lo, 0xB1), KM(K2, 1))
#define EX2(K2)  cex(hi, lo, hi, lo, XD(hi, 0x4E), XD(lo, 0x4E), KM(K2, 2))
#define EX4(K2)  cex(hi, lo, hi, lo, XS(hi, 0x101F), XS(lo, 0x101F), KM(K2, 4))
#define EX8(K2)  cex(hi, lo, hi, lo, XS(hi, 0x201F), XS(lo, 0x201F), KM(K2, 8))
#if __has_builtin(__builtin_amdgcn_permlane16_swap)
#define EX16(K2) { uint2v r_ = __builtin_amdgcn_permlane16_swap(hi, hi, false, false); \
                   uint2v s_ = __builtin_amdgcn_permlane16_swap(lo, lo, false, false); \
                   cex(hi, lo, (unsigned)r_[0], (unsigned)s_[0], (unsigned)r_[1], (unsigned)s_[1], KM(K2, 16)); }
#else
#define EX16(K2) cex(hi, lo, hi, lo, (unsigned)__shfl_xor((int)hi, 16), (unsigned)__shfl_xor((int)lo, 16), KM(K2, 16))
#endif
#if __has_builtin(__builtin_amdgcn_permlane32_swap)
#define EX32(K2) { uint2v r_ = __builtin_amdgcn_permlane32_swap(hi, hi, false, false); \
                   uint2v s_ = __builtin_amdgcn_permlane32_swap(lo, lo, false, false); \
                   cex(hi, lo, (unsigned)r_[0], (unsigned)s_[0], (unsigned)r_[1], (unsigned)s_[1], KM(K2, 32)); }
#else
#define EX32(K2) cex(hi, lo, hi, lo, (unsigned)__shfl_xor((int)hi, 32), (unsigned)__shfl_xor((int)lo, 32), KM(K2, 32))
#endif

// ---------------- exact (R1-proven) slow path ----------------
__device__ __forceinline__ void ins4(float vc, int jc,
                                     float& t0, float& t1, float& t2, float& t3,
                                     int& j0, int& j1, int& j2, int& j3) {
  bool b0 = vc > t0;
  float d0 = b0 ? t0 : vc; int e0 = b0 ? j0 : jc;
  t0 = b0 ? vc : t0;       j0 = b0 ? jc : j0;
  bool b1 = d0 > t1;
  float d1 = b1 ? t1 : d0; int e1 = b1 ? j1 : e0;
  t1 = b1 ? d0 : t1;       j1 = b1 ? e0 : j1;
  bool b2 = d1 > t2;
  float d2 = b2 ? t2 : d1; int e2 = b2 ? j2 : e1;
  t2 = b2 ? d1 : t2;       j2 = b2 ? e1 : j2;
  bool b3 = d2 > t3;
  t3 = b3 ? d2 : t3;       j3 = b3 ? e2 : j3;
}

__device__ __forceinline__ int wave_topk_exact(const float* __restrict__ Arow,
                                               const float* __restrict__ Drow,
                                               int lane) {
  float v[32];
  const float4* A4 = reinterpret_cast<const float4*>(Arow);
  const float4* D4 = reinterpret_cast<const float4*>(Drow);
#pragma unroll
  for (int c4 = 0; c4 < 8; ++c4) {
    float4 a = A4[c4 * 64 + lane];
    float4 d = D4[c4 * 64 + lane];
    v[c4 * 4 + 0] = __fadd_rn(fmaxf(a.x, 0.0f), __fmul_rn(d.x, 1e-4f));
    v[c4 * 4 + 1] = __fadd_rn(fmaxf(a.y, 0.0f), __fmul_rn(d.y, 1e-4f));
    v[c4 * 4 + 2] = __fadd_rn(fmaxf(a.z, 0.0f), __fmul_rn(d.z, 1e-4f));
    v[c4 * 4 + 3] = __fadd_rn(fmaxf(a.w, 0.0f), __fmul_rn(d.w, 1e-4f));
  }
  float t0 = -1.f, t1 = -1.f, t2 = -1.f, t3 = -1.f;
  int   j0 = 0,    j1 = 0,    j2 = 0,    j3 = 0;
#pragma unroll
  for (int c = 0; c < 32; ++c) {
    int jc = ((c >> 2) << 8) | (lane << 2) | (c & 3);
    ins4(v[c], jc, t0, t1, t2, t3, j0, j1, j2, j3);
  }
  unsigned consumed = 0;
  int jmine = 0;
#pragma unroll 1
  for (int it = 0; it < KSEL; ++it) {
    if (__any(t0 < 0.0f)) {
      if (t0 < 0.0f) {
        t0 = t1 = t2 = t3 = -1.f; j0 = j1 = j2 = j3 = 0;
#pragma unroll
        for (int c = 0; c < 32; ++c) {
          float vc = ((consumed >> c) & 1u) ? -1.0f : v[c];
          int jc = ((c >> 2) << 8) | (lane << 2) | (c & 3);
          ins4(vc, jc, t0, t1, t2, t3, j0, j1, j2, j3);
        }
      }
    }
    float m = t0;
#pragma unroll
    for (int off = 32; off; off >>= 1) m = fmaxf(m, __shfl_xor(m, off));
    int cj = (t0 == m) ? j0 : 0x7fffffff;
#pragma unroll
    for (int off = 32; off; off >>= 1) cj = min(cj, __shfl_xor(cj, off));
    if (lane == it) jmine = cj;
    if (((cj >> 2) & 63) == lane) {
      int c = ((cj >> 8) << 2) | (cj & 3);
      consumed |= (1u << c);
      t0 = t1; j0 = j1; t1 = t2; j1 = j2; t2 = t3; j2 = j3; t3 = -1.f; j3 = 0;
    }
  }
  return jmine;
}

// ---------------- fast pass 1: A only, no dope ----------------
__global__ void __launch_bounds__(256)
topk_fast(const float* __restrict__ A,
          float* __restrict__ wval, int* __restrict__ widx,
          float* __restrict__ wdinv, int* __restrict__ wflag) {
  __shared__ unsigned long long cand[4][64];
  __shared__ unsigned scnt[4];
  const float T = 2.05f;
  int lane = threadIdx.x & 63;
  int w = threadIdx.x >> 6;
  int r = blockIdx.x * 4 + w;
  size_t base = (size_t)r * N;
  const float4* A4 = reinterpret_cast<const float4*>(A + base);

  float4 a0 = A4[lane],       a1 = A4[64 + lane],  a2 = A4[128 + lane], a3 = A4[192 + lane];
  float4 a4 = A4[256 + lane], a5 = A4[320 + lane], a6 = A4[384 + lane], a7 = A4[448 + lane];

  cand[w][lane] = 0ull;        // padding sorts to the bottom (real keys > T > 0)
  if (lane == 0) scnt[w] = 0u;

  // Candidate push: key = relu(a) only. LDS atomic allocates a slot; slot order
  // is nondeterministic but the bitonic sort canonicalizes it.
#define PUSH1(AV, J) do {                                                      \
    float k_ = fmaxf((AV), 0.0f);                                              \
    if (k_ > T) {                                                              \
      unsigned p_ = atomicAdd(&scnt[w], 1u);                                   \
      if (p_ < 64u)                                                            \
        cand[w][p_] = ((unsigned long long)__float_as_uint(k_) << 32) |        \
                      (unsigned)(2047 - (J));                                  \
    }                                                                          \
  } while (0)
#define PUSH4(AA, C4) do {                                                     \
    int jb_ = ((C4) << 8) | (lane << 2);                                       \
    PUSH1(AA.x, jb_ + 0);                                                      \
    PUSH1(AA.y, jb_ + 1);                                                      \
    PUSH1(AA.z, jb_ + 2);                                                      \
    PUSH1(AA.w, jb_ + 3);                                                      \
  } while (0)

  PUSH4(a0, 0); PUSH4(a1, 1); PUSH4(a2, 2); PUSH4(a3, 3);
  PUSH4(a4, 4); PUSH4(a5, 5); PUSH4(a6, 6); PUSH4(a7, 7);
#undef PUSH4
#undef PUSH1

  // wave-private LDS; drain DS pipe before cross-lane reads
  __asm__ __volatile__("s_waitcnt lgkmcnt(0)" ::: "memory");
  unsigned cnt = scnt[w];
  unsigned long long kv = cand[w][lane];
  unsigned hi = (unsigned)(kv >> 32), lo = (unsigned)kv;

  // 64-lane bitonic sort, descending by (a'bits, 2047-j)
  EX1(2);
  EX2(4);  EX1(4);
  EX4(8);  EX2(8);  EX1(8);
  EX8(16); EX4(16); EX2(16); EX1(16);
  EX16(32); EX8(32); EX4(32); EX2(32); EX1(32);
  EX32(64); EX16(64); EX8(64); EX4(64); EX2(64); EX1(64);

  // Set-exactness guard: doped keys shift by at most +1e-4 (exact fp32 bound).
  float a19 = __uint_as_float(read_lane_u32(hi, 19));
  float a20 = __uint_as_float(read_lane_u32(hi, 20));
  bool decided = (a19 > __fadd_rn(a20, 1e-4f)) && (a19 > __fadd_rn(T, 1e-4f));
  bool bad = (cnt < (unsigned)KSEL) || (cnt > 64u) || !decided;

  float val = (lane < KSEL) ? __uint_as_float(hi) : 0.0f;  // sorted key IS relu(a)
  float s = val;
#pragma unroll
  for (int off = 32; off; off >>= 1) s += __shfl_xor(s, off);
  float dinv = (float)(1.0 / sqrt(1.0 + (double)s));       // row sum >= 1, never inf

  if (lane < KSEL) {
    wval[r * KSEL + lane] = val;
    widx[r * KSEL + lane] = 2047 - (int)lo;
  }
  if (lane == 0) {
    wdinv[r] = dinv;
    wflag[r] = bad ? 1 : 0;
  }
}

// ---------------- cleanup: scan flags, redo flagged rows exactly (reads A+D) ----------------
__global__ void __launch_bounds__(256)
cleanup_flags(const float* __restrict__ A, const float* __restrict__ D,
              const int* __restrict__ wflag,
              float* __restrict__ wval, int* __restrict__ widx,
              float* __restrict__ wdinv) {
  int lane = threadIdx.x & 63;
  int gw = (blockIdx.x * 256 + threadIdx.x) >> 6;   // global wave id, 0..511
  int rbase = gw * 64;
  if (rbase >= NR) return;
  int f = wflag[rbase + lane];
  unsigned long long m = __ballot(f != 0);
  while (m) {
    int b = (int)__builtin_ctzll(m);
    m &= m - 1ull;
    int r = rbase + b;
    size_t base = (size_t)r * N;
    int jm = wave_topk_exact(A + base, D + base, lane);
    float val = 0.0f;
    if (lane < KSEL) val = fmaxf(A[base + jm], 0.0f);
    float s = (lane < KSEL) ? val : 0.0f;
#pragma unroll
    for (int off = 32; off; off >>= 1) s += __shfl_xor(s, off);
    float dinv = (float)(1.0 / sqrt(1.0 + (double)s));
    if (lane < KSEL) {
      wval[r * KSEL + lane] = val;
      widx[r * KSEL + lane] = jm;
    }
    if (lane == 0) wdinv[r] = dinv;
  }
}

// ---------------- pass 2: dense scatter (R1-proven) ----------------
__global__ void __launch_bounds__(256)
scatter_pass2(const float* __restrict__ wval, const int* __restrict__ widx,
              const float* __restrict__ wdinv, float* __restrict__ out) {
  __shared__ float row[N];
  int r = blockIdx.x;
  int i = r & (N - 1);
  int tid = threadIdx.x;
  float4* rv = reinterpret_cast<float4*>(row);
  float4 z = make_float4(0.f, 0.f, 0.f, 0.f);
  rv[tid] = z;
  rv[tid + 256] = z;
  __syncthreads();
  float di = wdinv[r];
  if (tid < KSEL) {
    int j   = widx[r * KSEL + tid];
    float v = wval[r * KSEL + tid];
    float dj = wdinv[(r & ~(N - 1)) + j];
    atomicAdd(&row[j], di * v * dj);          // may collide with diagonal only
  } else if (tid == KSEL) {
    atomicAdd(&row[i], di * di);              // the +I term
  }
  __syncthreads();
  float4* o4 = reinterpret_cast<float4*>(out + (size_t)r * N);
  o4[tid] = rv[tid];
  o4[tid + 256] = rv[tid + 256];
}

// ---------------- fallback (tiny ws): exact fused path, R1-proven ----------------
__global__ void __launch_bounds__(256)
topk_exact_pass1(const float* __restrict__ A, const float* __restrict__ D,
                 float* __restrict__ wdinv) {
  int lane = threadIdx.x & 63;
  int r = blockIdx.x * 4 + (threadIdx.x >> 6);
  size_t base = (size_t)r * N;
  int jm = wave_topk_exact(A + base, D + base, lane);
  float val = 0.0f;
  if (lane < KSEL) val = fmaxf(A[base + jm], 0.0f);
  float s = (lane < KSEL) ? val : 0.0f;
#pragma unroll
  for (int off = 32; off; off >>= 1) s += __shfl_xor(s, off);
  float dinv = (float)(1.0 / sqrt(1.0 + (double)s));
  if (lane == 0) wdinv[r] = dinv;
}

__global__ void __launch_bounds__(256)
fallback_pass2(const float* __restrict__ A, const float* __restrict__ D,
               const float* __restrict__ wdinv, float* __restrict__ out) {
  __shared__ float rows[4][N];
  int lane = threadIdx.x & 63;
  int w = threadIdx.x >> 6;
  int r = blockIdx.x * 4 + w;
  size_t base = (size_t)r * N;
  int i = r & (N - 1);
  int jm = wave_topk_exact(A + base, D + base, lane);
  float val = 0.0f;
  if (lane < KSEL) val = fmaxf(A[base + jm], 0.0f);
  float s = (lane < KSEL) ? val : 0.0f;
#pragma unroll
  for (int off = 32; off; off >>= 1) s += __shfl_xor(s, off);
  float di = (float)(1.0 / sqrt(1.0 + (double)s));
  float4* rv = reinterpret_cast<float4*>(rows[w]);
  float4 z = make_float4(0.f, 0.f, 0.f, 0.f);
#pragma unroll
  for (int q = 0; q < 8; ++q) rv[q * 64 + lane] = z;
  __syncthreads();
  if (lane < KSEL) {
    float dj = wdinv[(r & ~(N - 1)) + jm];
    atomicAdd(&rows[w][jm], di * val * dj);
  } else if (lane == KSEL) {
    atomicAdd(&rows[w][i], di * di);
  }
  __syncthreads();
  float4* o4 = reinterpret_cast<float4*>(out + base);
#pragma unroll
  for (int q = 0; q < 8; ++q) o4[q * 64 + lane] = rv[q * 64 + lane];
}

extern "C" void kernel_launch(void* const* d_in, const int* in_sizes, int n_in,
                              void* d_out, int out_size, void* d_ws, size_t ws_size,
                              hipStream_t stream) {
  const float* A = (const float*)d_in[0];
  const float* D = (const float*)d_in[1];
  float* out = (float*)d_out;
  char* ws = (char*)d_ws;
  size_t off_val  = 0;
  size_t off_idx  = off_val + (size_t)NR * KSEL * sizeof(float);
  size_t off_dinv = off_idx + (size_t)NR * KSEL * sizeof(int);
  size_t off_flag = off_dinv + (size_t)NR * sizeof(float);
  size_t total    = off_flag + (size_t)NR * sizeof(int);
  if (ws_size >= total) {
    float* wval  = (float*)(ws + off_val);
    int*   widx  = (int*)(ws + off_idx);
    float* wdinv = (float*)(ws + off_dinv);
    int*   wflag = (int*)(ws + off_flag);
    topk_fast<<<NR / 4, 256, 0, stream>>>(A, wval, widx, wdinv, wflag);
    cleanup_flags<<<128, 256, 0, stream>>>(A, D, wflag, wval, widx, wdinv);
    scatter_pass2<<<NR, 256, 0, stream>>>(wval, widx, wdinv, out);
  } else {
    float* wdinv = (float*)ws;
    topk_exact_pass1<<<NR / 4, 256, 0, stream>>>(A, D, wdinv);
    fallback_pass2<<<NR / 4, 256, 0, stream>>>(A, D, wdinv, out);
  }
}

// Round 6
// 158.611 us; speedup vs baseline: 1.3330x; 1.0630x over previous
//
#include <hip/hip_runtime.h>

// _GSPostProcessor: out = D^{-1/2} (topk20(relu(A) + dope*1e-4)*relu(A) + I) D^{-1/2}
// B=16, N=2048, K=20.
// R6 structure (2 kernels):
//  topk_fast  : wave-per-row, A-only read (dope-free set-exactness guard, R5-proven).
//               Rows where the guard can't certify the set (~0.3%) redo the exact
//               R1-proven doped path INLINE (wave-uniform branch, reads that row's dope).
//               Emits final wval/widx/wdinv.
//  scatter_reg: block-per-row, register compose (no LDS/atomics/syncs): thread t owns
//               cols {t, t+256, ...}; diagonal di*di plus <=20 hit-tested di*val*dj;
//               8 coalesced dword stores per thread. Same additive formula as the
//               absmax=0.0-proven LDS scatter (2-term fp32 add is order-invariant).

static constexpr int N    = 2048;
static constexpr int KSEL = 20;
static constexpr int NR   = 16 * 2048;   // B*N rows

typedef unsigned int uint2v __attribute__((ext_vector_type(2)));

// ---------------- cross-lane primitives ----------------
#if __has_builtin(__builtin_amdgcn_mov_dpp)
#define XD(v, ctrl) ((unsigned)__builtin_amdgcn_mov_dpp((int)(v), (ctrl), 0xF, 0xF, false))
#else
#define XD(v, ctrl) ((unsigned)__shfl_xor((int)(v), ((ctrl) == 0xB1 ? 1 : 2)))
#endif
#if __has_builtin(__builtin_amdgcn_ds_swizzle)
#define XS(v, imm) ((unsigned)__builtin_amdgcn_ds_swizzle((int)(v), (imm)))
#else
#define XS(v, imm) ((unsigned)__shfl_xor((int)(v), (((imm) >> 10) & 0x1F)))
#endif

__device__ __forceinline__ unsigned read_lane_u32(unsigned v, int srclane) {
#if __has_builtin(__builtin_amdgcn_readlane)
  return (unsigned)__builtin_amdgcn_readlane((int)v, srclane);
#else
  return (unsigned)__shfl((int)v, srclane, 64);
#endif
}

// compare-exchange: {A,B} = {self, partner} (order irrelevant); keep max iff km.
__device__ __forceinline__ void cex(unsigned& hi, unsigned& lo,
                                    unsigned Ahi, unsigned Alo,
                                    unsigned Bhi, unsigned Blo, bool km) {
  unsigned long long Av = ((unsigned long long)Ahi << 32) | Alo;
  unsigned long long Bv = ((unsigned long long)Bhi << 32) | Blo;
  bool sel = (km == (Av > Bv));
  hi = sel ? Ahi : Bhi;
  lo = sel ? Alo : Blo;
}

#define KM(K2, J) ((((lane & (J)) == 0)) != (((lane & (K2)) != 0)))
#define EX1(K2)  cex(hi, lo, hi, lo, XD(hi, 0xB1), XD(lo, 0xB1), KM(K2, 1))
#define EX2(K2)  cex(hi, lo, hi, lo, XD(hi, 0x4E), XD(lo, 0x4E), KM(K2, 2))
#define EX4(K2)  cex(hi, lo, hi, lo, XS(hi, 0x101F), XS(lo, 0x101F), KM(K2, 4))
#define EX8(K2)  cex(hi, lo, hi, lo, XS(hi, 0x201F), XS(lo, 0x201F), KM(K2, 8))
#if __has_builtin(__builtin_amdgcn_permlane16_swap)
#define EX16(K2) { uint2v r_ = __builtin_amdgcn_permlane16_swap(hi, hi, false, false); \
                   uint2v s_ = __builtin_amdgcn_permlane16_swap(lo, lo, false, false); \
                   cex(hi, lo, (unsigned)r_[0], (unsigned)s_[0], (unsigned)r_[1], (unsigned)s_[1], KM(K2, 16)); }
#else
#define EX16(K2) cex(hi, lo, hi, lo, (unsigned)__shfl_xor((int)hi, 16), (unsigned)__shfl_xor((int)lo, 16), KM(K2, 16))
#endif
#if __has_builtin(__builtin_amdgcn_permlane32_swap)
#define EX32(K2) { uint2v r_ = __builtin_amdgcn_permlane32_swap(hi, hi, false, false); \
                   uint2v s_ = __builtin_amdgcn_permlane32_swap(lo, lo, false, false); \
                   cex(hi, lo, (unsigned)r_[0], (unsigned)s_[0], (unsigned)r_[1], (unsigned)s_[1], KM(K2, 32)); }
#else
#define EX32(K2) cex(hi, lo, hi, lo, (unsigned)__shfl_xor((int)hi, 32), (unsigned)__shfl_xor((int)lo, 32), KM(K2, 32))
#endif

// ---------------- exact (R1-proven) doped path ----------------
__device__ __forceinline__ void ins4(float vc, int jc,
                                     float& t0, float& t1, float& t2, float& t3,
                                     int& j0, int& j1, int& j2, int& j3) {
  bool b0 = vc > t0;
  float d0 = b0 ? t0 : vc; int e0 = b0 ? j0 : jc;
  t0 = b0 ? vc : t0;       j0 = b0 ? jc : j0;
  bool b1 = d0 > t1;
  float d1 = b1 ? t1 : d0; int e1 = b1 ? j1 : e0;
  t1 = b1 ? d0 : t1;       j1 = b1 ? e0 : j1;
  bool b2 = d1 > t2;
  float d2 = b2 ? t2 : d1; int e2 = b2 ? j2 : e1;
  t2 = b2 ? d1 : t2;       j2 = b2 ? e1 : j2;
  bool b3 = d2 > t3;
  t3 = b3 ? d2 : t3;       j3 = b3 ? e2 : j3;
}

__device__ __forceinline__ int wave_topk_exact(const float* __restrict__ Arow,
                                               const float* __restrict__ Drow,
                                               int lane) {
  float v[32];
  const float4* A4 = reinterpret_cast<const float4*>(Arow);
  const float4* D4 = reinterpret_cast<const float4*>(Drow);
#pragma unroll
  for (int c4 = 0; c4 < 8; ++c4) {
    float4 a = A4[c4 * 64 + lane];
    float4 d = D4[c4 * 64 + lane];
    v[c4 * 4 + 0] = __fadd_rn(fmaxf(a.x, 0.0f), __fmul_rn(d.x, 1e-4f));
    v[c4 * 4 + 1] = __fadd_rn(fmaxf(a.y, 0.0f), __fmul_rn(d.y, 1e-4f));
    v[c4 * 4 + 2] = __fadd_rn(fmaxf(a.z, 0.0f), __fmul_rn(d.z, 1e-4f));
    v[c4 * 4 + 3] = __fadd_rn(fmaxf(a.w, 0.0f), __fmul_rn(d.w, 1e-4f));
  }
  float t0 = -1.f, t1 = -1.f, t2 = -1.f, t3 = -1.f;
  int   j0 = 0,    j1 = 0,    j2 = 0,    j3 = 0;
#pragma unroll
  for (int c = 0; c < 32; ++c) {
    int jc = ((c >> 2) << 8) | (lane << 2) | (c & 3);
    ins4(v[c], jc, t0, t1, t2, t3, j0, j1, j2, j3);
  }
  unsigned consumed = 0;
  int jmine = 0;
#pragma unroll 1
  for (int it = 0; it < KSEL; ++it) {
    if (__any(t0 < 0.0f)) {
      if (t0 < 0.0f) {
        t0 = t1 = t2 = t3 = -1.f; j0 = j1 = j2 = j3 = 0;
#pragma unroll
        for (int c = 0; c < 32; ++c) {
          float vc = ((consumed >> c) & 1u) ? -1.0f : v[c];
          int jc = ((c >> 2) << 8) | (lane << 2) | (c & 3);
          ins4(vc, jc, t0, t1, t2, t3, j0, j1, j2, j3);
        }
      }
    }
    float m = t0;
#pragma unroll
    for (int off = 32; off; off >>= 1) m = fmaxf(m, __shfl_xor(m, off));
    int cj = (t0 == m) ? j0 : 0x7fffffff;
#pragma unroll
    for (int off = 32; off; off >>= 1) cj = min(cj, __shfl_xor(cj, off));
    if (lane == it) jmine = cj;
    if (((cj >> 2) & 63) == lane) {
      int c = ((cj >> 8) << 2) | (cj & 3);
      consumed |= (1u << c);
      t0 = t1; j0 = j1; t1 = t2; j1 = j2; t2 = t3; j2 = j3; t3 = -1.f; j3 = 0;
    }
  }
  return jmine;
}

// ---------------- pass 1: A-only fast path + inline exact redo ----------------
__global__ void __launch_bounds__(256)
topk_fast(const float* __restrict__ A, const float* __restrict__ D,
          float* __restrict__ wval, int* __restrict__ widx,
          float* __restrict__ wdinv) {
  __shared__ unsigned long long cand[4][64];
  __shared__ unsigned scnt[4];
  const float T = 2.05f;
  int lane = threadIdx.x & 63;
  int w = threadIdx.x >> 6;
  int r = blockIdx.x * 4 + w;
  size_t base = (size_t)r * N;
  const float4* A4 = reinterpret_cast<const float4*>(A + base);

  float4 a0 = A4[lane],       a1 = A4[64 + lane],  a2 = A4[128 + lane], a3 = A4[192 + lane];
  float4 a4 = A4[256 + lane], a5 = A4[320 + lane], a6 = A4[384 + lane], a7 = A4[448 + lane];

  cand[w][lane] = 0ull;        // padding sorts to the bottom (real keys > T > 0)
  if (lane == 0) scnt[w] = 0u;

#define PUSH1(AV, J) do {                                                      \
    float k_ = fmaxf((AV), 0.0f);                                              \
    if (k_ > T) {                                                              \
      unsigned p_ = atomicAdd(&scnt[w], 1u);                                   \
      if (p_ < 64u)                                                            \
        cand[w][p_] = ((unsigned long long)__float_as_uint(k_) << 32) |        \
                      (unsigned)(2047 - (J));                                  \
    }                                                                          \
  } while (0)
#define PUSH4(AA, C4) do {                                                     \
    int jb_ = ((C4) << 8) | (lane << 2);                                       \
    PUSH1(AA.x, jb_ + 0);                                                      \
    PUSH1(AA.y, jb_ + 1);                                                      \
    PUSH1(AA.z, jb_ + 2);                                                      \
    PUSH1(AA.w, jb_ + 3);                                                      \
  } while (0)

  PUSH4(a0, 0); PUSH4(a1, 1); PUSH4(a2, 2); PUSH4(a3, 3);
  PUSH4(a4, 4); PUSH4(a5, 5); PUSH4(a6, 6); PUSH4(a7, 7);
#undef PUSH4
#undef PUSH1

  // wave-private LDS; drain DS pipe before cross-lane reads
  __asm__ __volatile__("s_waitcnt lgkmcnt(0)" ::: "memory");
  unsigned cnt = scnt[w];
  unsigned long long kv = cand[w][lane];
  unsigned hi = (unsigned)(kv >> 32), lo = (unsigned)kv;

  // 64-lane bitonic sort, descending by (a'bits, 2047-j)
  EX1(2);
  EX2(4);  EX1(4);
  EX4(8);  EX2(8);  EX1(8);
  EX8(16); EX4(16); EX2(16); EX1(16);
  EX16(32); EX8(32); EX4(32); EX2(32); EX1(32);
  EX32(64); EX16(64); EX8(64); EX4(64); EX2(64); EX1(64);

  // Set-exactness guard: doped keys shift by at most +1e-4 (exact fp32 bound).
  float a19 = __uint_as_float(read_lane_u32(hi, 19));
  float a20 = __uint_as_float(read_lane_u32(hi, 20));
  bool decided = (a19 > __fadd_rn(a20, 1e-4f)) && (a19 > __fadd_rn(T, 1e-4f));
  bool bad = (cnt < (unsigned)KSEL) || (cnt > 64u) || !decided;  // wave-uniform

  int jsel = 2047 - (int)lo;
  float val = (lane < KSEL) ? __uint_as_float(hi) : 0.0f;  // sorted key IS relu(a)

  if (bad) {                    // ~0.3% of waves: exact doped redo (reads this row's dope)
    int jm = wave_topk_exact(A + base, D + base, lane);
    jsel = jm;
    val = (lane < KSEL) ? fmaxf(A[base + jm], 0.0f) : 0.0f;
  }

  float s = val;
#pragma unroll
  for (int off = 32; off; off >>= 1) s += __shfl_xor(s, off);
  float dinv = (float)(1.0 / sqrt(1.0 + (double)s));       // row sum >= 1, never inf

  if (lane < KSEL) {
    wval[r * KSEL + lane] = val;
    widx[r * KSEL + lane] = jsel;
  }
  if (lane == 0) wdinv[r] = dinv;
}

// ---------------- pass 2: register-compose scatter (no LDS, no atomics) ----------------
__global__ void __launch_bounds__(256)
scatter_reg(const float* __restrict__ wval, const int* __restrict__ widx,
            const float* __restrict__ wdinv, float* __restrict__ out) {
  int r = blockIdx.x;
  int tid = threadIdx.x;
  int i = r & (N - 1);
  int bb = r & ~(N - 1);                 // batch row-base
  float di = wdinv[r];

  float v0 = 0.f, v1 = 0.f, v2 = 0.f, v3 = 0.f,
        v4 = 0.f, v5 = 0.f, v6 = 0.f, v7 = 0.f;
  // diagonal term first (same additive composition as the proven LDS scatter;
  // 2-term fp32 add is order-invariant bitwise)
  if ((i & 255) == tid) {
    float dd = di * di;
    switch (i >> 8) {
      case 0: v0 = dd; break; case 1: v1 = dd; break;
      case 2: v2 = dd; break; case 3: v3 = dd; break;
      case 4: v4 = dd; break; case 5: v5 = dd; break;
      case 6: v6 = dd; break; case 7: v7 = dd; break;
    }
  }
#pragma unroll
  for (int t = 0; t < KSEL; ++t) {
    int j = widx[r * KSEL + t];          // uniform -> scalar load
    if ((j & 255) == tid) {              // <=20 of 256 threads hit
      float c = di * wval[r * KSEL + t] * wdinv[bb + j];
      switch (j >> 8) {
        case 0: v0 += c; break; case 1: v1 += c; break;
        case 2: v2 += c; break; case 3: v3 += c; break;
        case 4: v4 += c; break; case 5: v5 += c; break;
        case 6: v6 += c; break; case 7: v7 += c; break;
      }
    }
  }
  float* o = out + (size_t)r * N;
  o[tid]        = v0;  o[256 + tid]  = v1;
  o[512 + tid]  = v2;  o[768 + tid]  = v3;
  o[1024 + tid] = v4;  o[1280 + tid] = v5;
  o[1536 + tid] = v6;  o[1792 + tid] = v7;
}

// ---------------- fallback (tiny ws): exact fused path, R1-proven ----------------
__global__ void __launch_bounds__(256)
topk_exact_pass1(const float* __restrict__ A, const float* __restrict__ D,
                 float* __restrict__ wdinv) {
  int lane = threadIdx.x & 63;
  int r = blockIdx.x * 4 + (threadIdx.x >> 6);
  size_t base = (size_t)r * N;
  int jm = wave_topk_exact(A + base, D + base, lane);
  float val = 0.0f;
  if (lane < KSEL) val = fmaxf(A[base + jm], 0.0f);
  float s = (lane < KSEL) ? val : 0.0f;
#pragma unroll
  for (int off = 32; off; off >>= 1) s += __shfl_xor(s, off);
  float dinv = (float)(1.0 / sqrt(1.0 + (double)s));
  if (lane == 0) wdinv[r] = dinv;
}

__global__ void __launch_bounds__(256)
fallback_pass2(const float* __restrict__ A, const float* __restrict__ D,
               const float* __restrict__ wdinv, float* __restrict__ out) {
  __shared__ float rows[4][N];
  int lane = threadIdx.x & 63;
  int w = threadIdx.x >> 6;
  int r = blockIdx.x * 4 + w;
  size_t base = (size_t)r * N;
  int i = r & (N - 1);
  int jm = wave_topk_exact(A + base, D + base, lane);
  float val = 0.0f;
  if (lane < KSEL) val = fmaxf(A[base + jm], 0.0f);
  float s = (lane < KSEL) ? val : 0.0f;
#pragma unroll
  for (int off = 32; off; off >>= 1) s += __shfl_xor(s, off);
  float di = (float)(1.0 / sqrt(1.0 + (double)s));
  float4* rv = reinterpret_cast<float4*>(rows[w]);
  float4 z = make_float4(0.f, 0.f, 0.f, 0.f);
#pragma unroll
  for (int q = 0; q < 8; ++q) rv[q * 64 + lane] = z;
  __syncthreads();
  if (lane < KSEL) {
    float dj = wdinv[(r & ~(N - 1)) + jm];
    atomicAdd(&rows[w][jm], di * val * dj);
  } else if (lane == KSEL) {
    atomicAdd(&rows[w][i], di * di);
  }
  __syncthreads();
  float4* o4 = reinterpret_cast<float4*>(out + base);
#pragma unroll
  for (int q = 0; q < 8; ++q) o4[q * 64 + lane] = rv[q * 64 + lane];
}

extern "C" void kernel_launch(void* const* d_in, const int* in_sizes, int n_in,
                              void* d_out, int out_size, void* d_ws, size_t ws_size,
                              hipStream_t stream) {
  const float* A = (const float*)d_in[0];
  const float* D = (const float*)d_in[1];
  float* out = (float*)d_out;
  char* ws = (char*)d_ws;
  size_t off_val  = 0;
  size_t off_idx  = off_val + (size_t)NR * KSEL * sizeof(float);
  size_t off_dinv = off_idx + (size_t)NR * KSEL * sizeof(int);
  size_t total    = off_dinv + (size_t)NR * sizeof(float);
  if (ws_size >= total) {
    float* wval  = (float*)(ws + off_val);
    int*   widx  = (int*)(ws + off_idx);
    float* wdinv = (float*)(ws + off_dinv);
    topk_fast<<<NR / 4, 256, 0, stream>>>(A, D, wval, widx, wdinv);
    scatter_reg<<<NR, 256, 0, stream>>>(wval, widx, wdinv, out);
  } else {
    float* wdinv = (float*)ws;
    topk_exact_pass1<<<NR / 4, 256, 0, stream>>>(A, D, wdinv);
    fallback_pass2<<<NR / 4, 256, 0, stream>>>(A, D, wdinv, out);
  }
}

// Round 7
// 126.852 us; speedup vs baseline: 1.6668x; 1.2504x over previous
//
#include <hip/hip_runtime.h>

// _GSPostProcessor: out = D^{-1/2} (topk20(relu(A) + dope*1e-4)*relu(A) + I) D^{-1/2}
// B=16, N=2048, K=20.
// R7 = R6 structure + non-temporal memory probe:
//  - pass1 A-row loads are nontemporal (A read exactly once; bypass L1 allocate path)
//  - scatter output stores are nontemporal (out never re-read; don't evict L3)
//  topk_fast  : wave-per-row, A-only read, set-exactness guard (R5/R6-proven);
//               uncertain rows (~0.3%) redo the exact R1-proven doped path inline.
//  scatter_reg: block-per-row register compose, 8 coalesced nt stores per thread.

static constexpr int N    = 2048;
static constexpr int KSEL = 20;
static constexpr int NR   = 16 * 2048;   // B*N rows

typedef unsigned int uint2v __attribute__((ext_vector_type(2)));
typedef float f32x4 __attribute__((ext_vector_type(4)));

#if __has_builtin(__builtin_nontemporal_load)
#define NT_LOAD(p) __builtin_nontemporal_load(p)
#else
#define NT_LOAD(p) (*(p))
#endif
#if __has_builtin(__builtin_nontemporal_store)
#define NT_STORE(v, p) __builtin_nontemporal_store((v), (p))
#else
#define NT_STORE(v, p) (*(p) = (v))
#endif

// ---------------- cross-lane primitives ----------------
#if __has_builtin(__builtin_amdgcn_mov_dpp)
#define XD(v, ctrl) ((unsigned)__builtin_amdgcn_mov_dpp((int)(v), (ctrl), 0xF, 0xF, false))
#else
#define XD(v, ctrl) ((unsigned)__shfl_xor((int)(v), ((ctrl) == 0xB1 ? 1 : 2)))
#endif
#if __has_builtin(__builtin_amdgcn_ds_swizzle)
#define XS(v, imm) ((unsigned)__builtin_amdgcn_ds_swizzle((int)(v), (imm)))
#else
#define XS(v, imm) ((unsigned)__shfl_xor((int)(v), (((imm) >> 10) & 0x1F)))
#endif

__device__ __forceinline__ unsigned read_lane_u32(unsigned v, int srclane) {
#if __has_builtin(__builtin_amdgcn_readlane)
  return (unsigned)__builtin_amdgcn_readlane((int)v, srclane);
#else
  return (unsigned)__shfl((int)v, srclane, 64);
#endif
}

// compare-exchange: {A,B} = {self, partner} (order irrelevant); keep max iff km.
__device__ __forceinline__ void cex(unsigned& hi, unsigned& lo,
                                    unsigned Ahi, unsigned Alo,
                                    unsigned Bhi, unsigned Blo, bool km) {
  unsigned long long Av = ((unsigned long long)Ahi << 32) | Alo;
  unsigned long long Bv = ((unsigned long long)Bhi << 32) | Blo;
  bool sel = (km == (Av > Bv));
  hi = sel ? Ahi : Bhi;
  lo = sel ? Alo : Blo;
}

#define KM(K2, J) ((((lane & (J)) == 0)) != (((lane & (K2)) != 0)))
#define EX1(K2)  cex(hi, lo, hi, lo, XD(hi, 0xB1), XD(lo, 0xB1), KM(K2, 1))
#define EX2(K2)  cex(hi, lo, hi, lo, XD(hi, 0x4E), XD(lo, 0x4E), KM(K2, 2))
#define EX4(K2)  cex(hi, lo, hi, lo, XS(hi, 0x101F), XS(lo, 0x101F), KM(K2, 4))
#define EX8(K2)  cex(hi, lo, hi, lo, XS(hi, 0x201F), XS(lo, 0x201F), KM(K2, 8))
#if __has_builtin(__builtin_amdgcn_permlane16_swap)
#define EX16(K2) { uint2v r_ = __builtin_amdgcn_permlane16_swap(hi, hi, false, false); \
                   uint2v s_ = __builtin_amdgcn_permlane16_swap(lo, lo, false, false); \
                   cex(hi, lo, (unsigned)r_[0], (unsigned)s_[0], (unsigned)r_[1], (unsigned)s_[1], KM(K2, 16)); }
#else
#define EX16(K2) cex(hi, lo, hi, lo, (unsigned)__shfl_xor((int)hi, 16), (unsigned)__shfl_xor((int)lo, 16), KM(K2, 16))
#endif
#if __has_builtin(__builtin_amdgcn_permlane32_swap)
#define EX32(K2) { uint2v r_ = __builtin_amdgcn_permlane32_swap(hi, hi, false, false); \
                   uint2v s_ = __builtin_amdgcn_permlane32_swap(lo, lo, false, false); \
                   cex(hi, lo, (unsigned)r_[0], (unsigned)s_[0], (unsigned)r_[1], (unsigned)s_[1], KM(K2, 32)); }
#else
#define EX32(K2) cex(hi, lo, hi, lo, (unsigned)__shfl_xor((int)hi, 32), (unsigned)__shfl_xor((int)lo, 32), KM(K2, 32))
#endif

// ---------------- exact (R1-proven) doped path ----------------
__device__ __forceinline__ void ins4(float vc, int jc,
                                     float& t0, float& t1, float& t2, float& t3,
                                     int& j0, int& j1, int& j2, int& j3) {
  bool b0 = vc > t0;
  float d0 = b0 ? t0 : vc; int e0 = b0 ? j0 : jc;
  t0 = b0 ? vc : t0;       j0 = b0 ? jc : j0;
  bool b1 = d0 > t1;
  float d1 = b1 ? t1 : d0; int e1 = b1 ? j1 : e0;
  t1 = b1 ? d0 : t1;       j1 = b1 ? e0 : j1;
  bool b2 = d1 > t2;
  float d2 = b2 ? t2 : d1; int e2 = b2 ? j2 : e1;
  t2 = b2 ? d1 : t2;       j2 = b2 ? e1 : j2;
  bool b3 = d2 > t3;
  t3 = b3 ? d2 : t3;       j3 = b3 ? e2 : j3;
}

__device__ __forceinline__ int wave_topk_exact(const float* __restrict__ Arow,
                                               const float* __restrict__ Drow,
                                               int lane) {
  float v[32];
  const float4* A4 = reinterpret_cast<const float4*>(Arow);
  const float4* D4 = reinterpret_cast<const float4*>(Drow);
#pragma unroll
  for (int c4 = 0; c4 < 8; ++c4) {
    float4 a = A4[c4 * 64 + lane];
    float4 d = D4[c4 * 64 + lane];
    v[c4 * 4 + 0] = __fadd_rn(fmaxf(a.x, 0.0f), __fmul_rn(d.x, 1e-4f));
    v[c4 * 4 + 1] = __fadd_rn(fmaxf(a.y, 0.0f), __fmul_rn(d.y, 1e-4f));
    v[c4 * 4 + 2] = __fadd_rn(fmaxf(a.z, 0.0f), __fmul_rn(d.z, 1e-4f));
    v[c4 * 4 + 3] = __fadd_rn(fmaxf(a.w, 0.0f), __fmul_rn(d.w, 1e-4f));
  }
  float t0 = -1.f, t1 = -1.f, t2 = -1.f, t3 = -1.f;
  int   j0 = 0,    j1 = 0,    j2 = 0,    j3 = 0;
#pragma unroll
  for (int c = 0; c < 32; ++c) {
    int jc = ((c >> 2) << 8) | (lane << 2) | (c & 3);
    ins4(v[c], jc, t0, t1, t2, t3, j0, j1, j2, j3);
  }
  unsigned consumed = 0;
  int jmine = 0;
#pragma unroll 1
  for (int it = 0; it < KSEL; ++it) {
    if (__any(t0 < 0.0f)) {
      if (t0 < 0.0f) {
        t0 = t1 = t2 = t3 = -1.f; j0 = j1 = j2 = j3 = 0;
#pragma unroll
        for (int c = 0; c < 32; ++c) {
          float vc = ((consumed >> c) & 1u) ? -1.0f : v[c];
          int jc = ((c >> 2) << 8) | (lane << 2) | (c & 3);
          ins4(vc, jc, t0, t1, t2, t3, j0, j1, j2, j3);
        }
      }
    }
    float m = t0;
#pragma unroll
    for (int off = 32; off; off >>= 1) m = fmaxf(m, __shfl_xor(m, off));
    int cj = (t0 == m) ? j0 : 0x7fffffff;
#pragma unroll
    for (int off = 32; off; off >>= 1) cj = min(cj, __shfl_xor(cj, off));
    if (lane == it) jmine = cj;
    if (((cj >> 2) & 63) == lane) {
      int c = ((cj >> 8) << 2) | (cj & 3);
      consumed |= (1u << c);
      t0 = t1; j0 = j1; t1 = t2; j1 = j2; t2 = t3; j2 = j3; t3 = -1.f; j3 = 0;
    }
  }
  return jmine;
}

// ---------------- pass 1: A-only fast path (nt loads) + inline exact redo ----------------
__global__ void __launch_bounds__(256)
topk_fast(const float* __restrict__ A, const float* __restrict__ D,
          float* __restrict__ wval, int* __restrict__ widx,
          float* __restrict__ wdinv) {
  __shared__ unsigned long long cand[4][64];
  __shared__ unsigned scnt[4];
  const float T = 2.05f;
  int lane = threadIdx.x & 63;
  int w = threadIdx.x >> 6;
  int r = blockIdx.x * 4 + w;
  size_t base = (size_t)r * N;
  const f32x4* A4 = reinterpret_cast<const f32x4*>(A + base);

  f32x4 a0 = NT_LOAD(A4 + lane);       f32x4 a1 = NT_LOAD(A4 + 64 + lane);
  f32x4 a2 = NT_LOAD(A4 + 128 + lane); f32x4 a3 = NT_LOAD(A4 + 192 + lane);
  f32x4 a4 = NT_LOAD(A4 + 256 + lane); f32x4 a5 = NT_LOAD(A4 + 320 + lane);
  f32x4 a6 = NT_LOAD(A4 + 384 + lane); f32x4 a7 = NT_LOAD(A4 + 448 + lane);

  cand[w][lane] = 0ull;        // padding sorts to the bottom (real keys > T > 0)
  if (lane == 0) scnt[w] = 0u;

#define PUSH1(AV, J) do {                                                      \
    float k_ = fmaxf((AV), 0.0f);                                              \
    if (k_ > T) {                                                              \
      unsigned p_ = atomicAdd(&scnt[w], 1u);                                   \
      if (p_ < 64u)                                                            \
        cand[w][p_] = ((unsigned long long)__float_as_uint(k_) << 32) |        \
                      (unsigned)(2047 - (J));                                  \
    }                                                                          \
  } while (0)
#define PUSH4(AA, C4) do {                                                     \
    int jb_ = ((C4) << 8) | (lane << 2);                                       \
    PUSH1(AA.x, jb_ + 0);                                                      \
    PUSH1(AA.y, jb_ + 1);                                                      \
    PUSH1(AA.z, jb_ + 2);                                                      \
    PUSH1(AA.w, jb_ + 3);                                                      \
  } while (0)

  PUSH4(a0, 0); PUSH4(a1, 1); PUSH4(a2, 2); PUSH4(a3, 3);
  PUSH4(a4, 4); PUSH4(a5, 5); PUSH4(a6, 6); PUSH4(a7, 7);
#undef PUSH4
#undef PUSH1

  // wave-private LDS; drain DS pipe before cross-lane reads
  __asm__ __volatile__("s_waitcnt lgkmcnt(0)" ::: "memory");
  unsigned cnt = scnt[w];
  unsigned long long kv = cand[w][lane];
  unsigned hi = (unsigned)(kv >> 32), lo = (unsigned)kv;

  // 64-lane bitonic sort, descending by (a'bits, 2047-j)
  EX1(2);
  EX2(4);  EX1(4);
  EX4(8);  EX2(8);  EX1(8);
  EX8(16); EX4(16); EX2(16); EX1(16);
  EX16(32); EX8(32); EX4(32); EX2(32); EX1(32);
  EX32(64); EX16(64); EX8(64); EX4(64); EX2(64); EX1(64);

  // Set-exactness guard: doped keys shift by at most +1e-4 (exact fp32 bound).
  float a19 = __uint_as_float(read_lane_u32(hi, 19));
  float a20 = __uint_as_float(read_lane_u32(hi, 20));
  bool decided = (a19 > __fadd_rn(a20, 1e-4f)) && (a19 > __fadd_rn(T, 1e-4f));
  bool bad = (cnt < (unsigned)KSEL) || (cnt > 64u) || !decided;  // wave-uniform

  int jsel = 2047 - (int)lo;
  float val = (lane < KSEL) ? __uint_as_float(hi) : 0.0f;  // sorted key IS relu(a)

  if (bad) {                    // ~0.3% of waves: exact doped redo (reads this row's dope)
    int jm = wave_topk_exact(A + base, D + base, lane);
    jsel = jm;
    val = (lane < KSEL) ? fmaxf(A[base + jm], 0.0f) : 0.0f;
  }

  float s = val;
#pragma unroll
  for (int off = 32; off; off >>= 1) s += __shfl_xor(s, off);
  float dinv = (float)(1.0 / sqrt(1.0 + (double)s));       // row sum >= 1, never inf

  if (lane < KSEL) {
    wval[r * KSEL + lane] = val;
    widx[r * KSEL + lane] = jsel;
  }
  if (lane == 0) wdinv[r] = dinv;
}

// ---------------- pass 2: register-compose scatter (nt stores) ----------------
__global__ void __launch_bounds__(256)
scatter_reg(const float* __restrict__ wval, const int* __restrict__ widx,
            const float* __restrict__ wdinv, float* __restrict__ out) {
  int r = blockIdx.x;
  int tid = threadIdx.x;
  int i = r & (N - 1);
  int bb = r & ~(N - 1);                 // batch row-base
  float di = wdinv[r];

  float v0 = 0.f, v1 = 0.f, v2 = 0.f, v3 = 0.f,
        v4 = 0.f, v5 = 0.f, v6 = 0.f, v7 = 0.f;
  // diagonal term first (same additive composition as the proven LDS scatter;
  // 2-term fp32 add is order-invariant bitwise)
  if ((i & 255) == tid) {
    float dd = di * di;
    switch (i >> 8) {
      case 0: v0 = dd; break; case 1: v1 = dd; break;
      case 2: v2 = dd; break; case 3: v3 = dd; break;
      case 4: v4 = dd; break; case 5: v5 = dd; break;
      case 6: v6 = dd; break; case 7: v7 = dd; break;
    }
  }
#pragma unroll
  for (int t = 0; t < KSEL; ++t) {
    int j = widx[r * KSEL + t];          // uniform -> scalar load
    if ((j & 255) == tid) {              // <=20 of 256 threads hit
      float c = di * wval[r * KSEL + t] * wdinv[bb + j];
      switch (j >> 8) {
        case 0: v0 += c; break; case 1: v1 += c; break;
        case 2: v2 += c; break; case 3: v3 += c; break;
        case 4: v4 += c; break; case 5: v5 += c; break;
        case 6: v6 += c; break; case 7: v7 += c; break;
      }
    }
  }
  float* o = out + (size_t)r * N;
  NT_STORE(v0, o + tid);         NT_STORE(v1, o + 256 + tid);
  NT_STORE(v2, o + 512 + tid);   NT_STORE(v3, o + 768 + tid);
  NT_STORE(v4, o + 1024 + tid);  NT_STORE(v5, o + 1280 + tid);
  NT_STORE(v6, o + 1536 + tid);  NT_STORE(v7, o + 1792 + tid);
}

// ---------------- fallback (tiny ws): exact fused path, R1-proven ----------------
__global__ void __launch_bounds__(256)
topk_exact_pass1(const float* __restrict__ A, const float* __restrict__ D,
                 float* __restrict__ wdinv) {
  int lane = threadIdx.x & 63;
  int r = blockIdx.x * 4 + (threadIdx.x >> 6);
  size_t base = (size_t)r * N;
  int jm = wave_topk_exact(A + base, D + base, lane);
  float val = 0.0f;
  if (lane < KSEL) val = fmaxf(A[base + jm], 0.0f);
  float s = (lane < KSEL) ? val : 0.0f;
#pragma unroll
  for (int off = 32; off; off >>= 1) s += __shfl_xor(s, off);
  float dinv = (float)(1.0 / sqrt(1.0 + (double)s));
  if (lane == 0) wdinv[r] = dinv;
}

__global__ void __launch_bounds__(256)
fallback_pass2(const float* __restrict__ A, const float* __restrict__ D,
               const float* __restrict__ wdinv, float* __restrict__ out) {
  __shared__ float rows[4][N];
  int lane = threadIdx.x & 63;
  int w = threadIdx.x >> 6;
  int r = blockIdx.x * 4 + w;
  size_t base = (size_t)r * N;
  int i = r & (N - 1);
  int jm = wave_topk_exact(A + base, D + base, lane);
  float val = 0.0f;
  if (lane < KSEL) val = fmaxf(A[base + jm], 0.0f);
  float s = (lane < KSEL) ? val : 0.0f;
#pragma unroll
  for (int off = 32; off; off >>= 1) s += __shfl_xor(s, off);
  float di = (float)(1.0 / sqrt(1.0 + (double)s));
  float4* rv = reinterpret_cast<float4*>(rows[w]);
  float4 z = make_float4(0.f, 0.f, 0.f, 0.f);
#pragma unroll
  for (int q = 0; q < 8; ++q) rv[q * 64 + lane] = z;
  __syncthreads();
  if (lane < KSEL) {
    float dj = wdinv[(r & ~(N - 1)) + jm];
    atomicAdd(&rows[w][jm], di * val * dj);
  } else if (lane == KSEL) {
    atomicAdd(&rows[w][i], di * di);
  }
  __syncthreads();
  float4* o4 = reinterpret_cast<float4*>(out + base);
#pragma unroll
  for (int q = 0; q < 8; ++q) o4[q * 64 + lane] = rv[q * 64 + lane];
}

extern "C" void kernel_launch(void* const* d_in, const int* in_sizes, int n_in,
                              void* d_out, int out_size, void* d_ws, size_t ws_size,
                              hipStream_t stream) {
  const float* A = (const float*)d_in[0];
  const float* D = (const float*)d_in[1];
  float* out = (float*)d_out;
  char* ws = (char*)d_ws;
  size_t off_val  = 0;
  size_t off_idx  = off_val + (size_t)NR * KSEL * sizeof(float);
  size_t off_dinv = off_idx + (size_t)NR * KSEL * sizeof(int);
  size_t total    = off_dinv + (size_t)NR * sizeof(float);
  if (ws_size >= total) {
    float* wval  = (float*)(ws + off_val);
    int*   widx  = (int*)(ws + off_idx);
    float* wdinv = (float*)(ws + off_dinv);
    topk_fast<<<NR / 4, 256, 0, stream>>>(A, D, wval, widx, wdinv);
    scatter_reg<<<NR, 256, 0, stream>>>(wval, widx, wdinv, out);
  } else {
    float* wdinv = (float*)ws;
    topk_exact_pass1<<<NR / 4, 256, 0, stream>>>(A, D, wdinv);
    fallback_pass2<<<NR / 4, 256, 0, stream>>>(A, D, wdinv, out);
  }
}